// Round 12
// baseline (492.058 us; speedup 1.0000x reference)
//
#include <hip/hip_runtime.h>
#include <math.h>

#define N_NODES 20000
#define E_EDGES 200000
#define K1_KEEP 10000
#define K2_KEEP 5000
#define HIDC 128
#define NHEAD 4
#define FDIM 512   // NHEAD*HIDC
#define NEG 0.2f
#define BSTRIDE 64 // bucket CSR stride; P(deg>64)~e^-64 for Binom(200k,1/20k)

__device__ __forceinline__ float leaky(float x){ return x > 0.f ? x : NEG * x; }
__device__ __forceinline__ float elu(float x){ return x > 0.f ? x : expm1f(x); }
// monotone float->uint key (ascending)
__device__ __forceinline__ unsigned ordkey(float f){
    unsigned u = __float_as_uint(f);
    return (u & 0x80000000u) ? ~u : (u | 0x80000000u);
}

// ---------------- GEMM: out[n x 512] = A[n x K] @ W[K x 512] ----------------
// 64xCOLB tile / 256 threads / KC=32 LDS stage / 4x(COLB/16) per thread.
// r8-r11 lessons: COLB=64 w/ 1256 blocks is the plateau (~105us, VALU 43%);
// raising DS:FMA costs waves/CU and nets zero (r9), MR=8 collapses occ (r7).
// Column layout {4tc, (+64)} -> 2-way LDS bank aliasing only (free on CDNA4).
// ATTN (COLB=128 only): fused per-row attention dots (col block == one head).
// GATHER: A row r is gidx[r] scaled by gsc[gidx[r]] (TopK pool gather fused).
template<int K, int COLB, bool ATTN, bool GATHER>
__global__ __launch_bounds__(256) void gemm_tile(const float* __restrict__ A,
        const float* __restrict__ W, float* __restrict__ out,
        const int* __restrict__ gidx, const float* __restrict__ gsc,
        const float* __restrict__ avS, const float* __restrict__ avD,
        float* __restrict__ asrc, float* __restrict__ adst, int n)
{
    constexpr int NR = COLB / 16;        // 8 or 4 cols per thread
    constexpr int WPT = COLB / 32;       // W-stage float4s per thread (4 or 2)
    constexpr int BPR = 512 / COLB;      // col blocks per row stripe
    __shared__ float At[32][68];         // transposed A tile (16B-aligned rows)
    __shared__ float Wt[32][COLB];
    int t = threadIdx.x;
    int bid = blockIdx.x;
    int row0 = (bid / BPR) * 64;
    int col0 = (bid % BPR) * COLB;
    int tr = t >> 4;       // 0..15 -> rows 4*tr..4*tr+3
    int tc = t & 15;       // cols {col0+4tc.. (+64 for NR==8)}
    float acc[4][NR] = {};

    // loop-invariant row indirection for A staging
    int arow[2]; float asc[2];
#pragma unroll
    for (int i = 0; i < 2; ++i){
        int r = (t + i * 256) >> 3;
        int gr = row0 + r;
        arow[i] = -1; asc[i] = 1.f;
        if (gr < n){
            if (GATHER){ arow[i] = gidx[gr]; asc[i] = gsc[arow[i]]; }
            else arow[i] = gr;
        }
    }

    float4 pa[2], pw[WPT];
    // prefetch first tile
#pragma unroll
    for (int i = 0; i < 2; ++i){
        int kq = (t + i * 256) & 7;
        pa[i] = make_float4(0.f, 0.f, 0.f, 0.f);
        if (arow[i] >= 0){
            pa[i] = *reinterpret_cast<const float4*>(&A[(size_t)arow[i] * K + kq * 4]);
            if (GATHER){ pa[i].x *= asc[i]; pa[i].y *= asc[i]; pa[i].z *= asc[i]; pa[i].w *= asc[i]; }
        }
    }
#pragma unroll
    for (int i = 0; i < WPT; ++i){
        int s = t + i * 256; int k = s / (COLB / 4), c4 = s % (COLB / 4);
        pw[i] = *reinterpret_cast<const float4*>(&W[(size_t)k * 512 + col0 + c4 * 4]);
    }

    for (int kc = 0; kc < K; kc += 32){
        // write staged regs to LDS
#pragma unroll
        for (int i = 0; i < 2; ++i){
            int s = t + i * 256; int r = s >> 3, kq = s & 7;
            At[kq * 4 + 0][r] = pa[i].x;
            At[kq * 4 + 1][r] = pa[i].y;
            At[kq * 4 + 2][r] = pa[i].z;
            At[kq * 4 + 3][r] = pa[i].w;
        }
#pragma unroll
        for (int i = 0; i < WPT; ++i){
            int s = t + i * 256; int k = s / (COLB / 4), c4 = s % (COLB / 4);
            *reinterpret_cast<float4*>(&Wt[k][c4 * 4]) = pw[i];
        }
        __syncthreads();
        if (kc + 32 < K){   // prefetch next tile while computing this one
            int kn = kc + 32;
#pragma unroll
            for (int i = 0; i < 2; ++i){
                int kq = (t + i * 256) & 7;
                pa[i] = make_float4(0.f, 0.f, 0.f, 0.f);
                if (arow[i] >= 0){
                    pa[i] = *reinterpret_cast<const float4*>(&A[(size_t)arow[i] * K + kn + kq * 4]);
                    if (GATHER){ pa[i].x *= asc[i]; pa[i].y *= asc[i]; pa[i].z *= asc[i]; pa[i].w *= asc[i]; }
                }
            }
#pragma unroll
            for (int i = 0; i < WPT; ++i){
                int s = t + i * 256; int k = s / (COLB / 4), c4 = s % (COLB / 4);
                pw[i] = *reinterpret_cast<const float4*>(&W[(size_t)(kn + k) * 512 + col0 + c4 * 4]);
            }
        }
#pragma unroll 8
        for (int kk = 0; kk < 32; ++kk){
            float4 a = *reinterpret_cast<const float4*>(&At[kk][tr * 4]);
            float af[4] = {a.x, a.y, a.z, a.w};
            float wf[NR];
            {
                float4 w0 = *reinterpret_cast<const float4*>(&Wt[kk][tc * 4]);
                wf[0] = w0.x; wf[1] = w0.y; wf[2] = w0.z; wf[3] = w0.w;
                if (NR == 8){
                    float4 w1 = *reinterpret_cast<const float4*>(&Wt[kk][tc * 4 + 64]);
                    wf[4] = w1.x; wf[5] = w1.y; wf[6] = w1.z; wf[7] = w1.w;
                }
            }
#pragma unroll
            for (int r = 0; r < 4; ++r)
#pragma unroll
                for (int c = 0; c < NR; ++c) acc[r][c] += af[r] * wf[c];
        }
        __syncthreads();
    }
#pragma unroll
    for (int r = 0; r < 4; ++r){
        int gr = row0 + 4 * tr + r;
        if (gr < n){
            *reinterpret_cast<float4*>(&out[(size_t)gr * 512 + col0 + tc * 4]) =
                make_float4(acc[r][0], acc[r][1], acc[r][2], acc[r][3]);
            if (NR == 8)
                *reinterpret_cast<float4*>(&out[(size_t)gr * 512 + col0 + 64 + tc * 4]) =
                    make_float4(acc[r][4], acc[r][5], acc[r][6], acc[r][7]);
        }
    }
    if (ATTN){
        int head = col0 >> 7;
        const float* as = avS + head * HIDC;
        const float* ad = avD + head * HIDC;
#pragma unroll
        for (int r = 0; r < 4; ++r){
            float s = 0.f, d = 0.f;
#pragma unroll
            for (int c = 0; c < 4; ++c){
                s += acc[r][c] * as[4 * tc + c];
                d += acc[r][c] * ad[4 * tc + c];
                s += acc[r][4 + c] * as[64 + 4 * tc + c];
                d += acc[r][4 + c] * ad[64 + 4 * tc + c];
            }
#pragma unroll
            for (int off = 1; off < 16; off <<= 1){ s += __shfl_xor(s, off); d += __shfl_xor(d, off); }
            int gr = row0 + 4 * tr + r;
            if (tc == 0 && gr < n){ asrc[gr * 4 + head] = s; adst[gr * 4 + head] = d; }
        }
    }
}

// ------------- attention scores: asrc[n][h], adst[n][h] ---------------------
__global__ __launch_bounds__(256) void attn_scores(const float* __restrict__ h,
        const float* __restrict__ a_src, const float* __restrict__ a_dst,
        float* __restrict__ asrc, float* __restrict__ adst, int n)
{
    int g = blockIdx.x * 4 + (threadIdx.x >> 6);
    int lane = threadIdx.x & 63;
    int node = g >> 2, head = g & 3;
    if (node >= n) return;
    const float* hp = h + (size_t)node * FDIM + head * HIDC;
    float v0 = hp[lane], v1 = hp[lane + 64];
    const float* as = a_src + head * HIDC;
    const float* ad = a_dst + head * HIDC;
    float s = v0 * as[lane] + v1 * as[lane + 64];
    float d = v0 * ad[lane] + v1 * ad[lane + 64];
#pragma unroll
    for (int off = 32; off > 0; off >>= 1){ s += __shfl_xor(s, off); d += __shfl_xor(d, off); }
    if (lane == 0){ asrc[node * 4 + head] = s; adst[node * 4 + head] = d; }
}

// ---------------- meta clear + pool-weight norm (block 0) -------------------
__global__ __launch_bounds__(256) void clear_meta(int* __restrict__ tmp, int n,
        const float* __restrict__ w, float* __restrict__ invn){
    __shared__ float red[4];
    int i = blockIdx.x * 256 + threadIdx.x;
    if (i < n) tmp[i] = 0;
    if (blockIdx.x == 0){
        int t = threadIdx.x;
        float s = w[t] * w[t] + w[t + 256] * w[t + 256];
#pragma unroll
        for (int off = 32; off > 0; off >>= 1) s += __shfl_xor(s, off);
        if ((t & 63) == 0) red[t >> 6] = s;
        __syncthreads();
        if (t == 0) *invn = rsqrtf(red[0] + red[1] + red[2] + red[3]);
    }
}

// bucketed CSR fill: no count/scan passes needed; tmp returns degrees.
__global__ void edge_fill(const int* __restrict__ src, const int* __restrict__ dst, int e,
                          int* __restrict__ tmp, int* __restrict__ csr){
    int i = blockIdx.x * 256 + threadIdx.x;
    if (i >= e) return;
    int d = dst[i];
    int pos = atomicAdd(&tmp[d], 1);
    if (pos < BSTRIDE) csr[d * BSTRIDE + pos] = src[i];
}

// ---- fused softmax-stats + aggregation + pool score, 1 node / 128 thr ------
// r12: wave 0 computes stats + per-edge alphas ONCE into LDS (r11's 2-wave
// split duplicated the 3 scatter-heavy stats passes — that duplication ate
// the gain). After one barrier both waves run a pure gather-FMA loop over
// their 256-feature half: no exps, no shuffles, 1 coalesced float4/lane/edge.
// FILTER: walk LAYER-1 bucket row of oldi[node]; keep srcs with remap>=0
// (exact: removed edges contribute exp->0 in the reference).
template<bool FILTER>
__global__ __launch_bounds__(128) void gat_fused(const float* __restrict__ h,
        const float* __restrict__ asrc, const float* __restrict__ adst,
        const int* __restrict__ degs, const int* __restrict__ csr,
        const int* __restrict__ oldi, const int* __restrict__ remap,
        const float* __restrict__ bias, const float* __restrict__ pw,
        const float* __restrict__ invn, float* __restrict__ out,
        float* __restrict__ score, int n)
{
    __shared__ float l_alph[BSTRIDE][4];
    __shared__ int   l_sidx[BSTRIDE];
    __shared__ float l_self[4];
    __shared__ float sred[2];
    int node = blockIdx.x;
    int wv   = threadIdx.x >> 6;
    int lane = threadIdx.x & 63;
    int od = FILTER ? oldi[node] : node;
    int deg = degs[od]; if (deg > BSTRIDE) deg = BSTRIDE;
    int e0 = od * BSTRIDE, e1 = e0 + deg;

    if (wv == 0){
        // ---- stats + alpha (single wave; lane = (edge, head)) ----
        int ph = lane & 3;
        int pe = lane >> 2;
        float adn  = adst[node * 4 + ph];
        float slog = leaky(asrc[node * 4 + ph] + adn);
        float mx = slog;
        for (int j = e0 + pe; j < e1; j += 16){
            int s = csr[j];
            if (FILTER){ s = remap[s]; if (s < 0) continue; }
            mx = fmaxf(mx, leaky(asrc[s * 4 + ph] + adn));
        }
#pragma unroll
        for (int off = 4; off < 64; off <<= 1) mx = fmaxf(mx, __shfl_xor(mx, off));
        float lsum = 0.f;
        for (int j = e0 + pe; j < e1; j += 16){
            int s = csr[j];
            if (FILTER){ s = remap[s]; if (s < 0) continue; }
            lsum += expf(leaky(asrc[s * 4 + ph] + adn) - mx);
        }
#pragma unroll
        for (int off = 4; off < 64; off <<= 1) lsum += __shfl_xor(lsum, off);
        float es  = expf(slog - mx);
        float inv = 1.f / (lsum + es);
        for (int base = 0; base < deg; base += 16){
            int cnt = deg - base; if (cnt > 16) cnt = 16;
            if (pe < cnt){
                int s = csr[e0 + base + pe];
                if (FILTER) s = remap[s];
                float a = 0.f;
                if (s >= 0) a = expf(leaky(asrc[s * 4 + ph] + adn) - mx) * inv;
                l_alph[base + pe][ph] = a;
                if (ph == 0) l_sidx[base + pe] = s;
            }
        }
        if (pe == 0) l_self[ph] = es * inv;
    }
    __syncthreads();

    // ---- aggregation: each wave owns 256 features ----
    int f0 = wv * 256 + lane * 4;
    int head = f0 >> 7;
    float4 acc;
    {
        float a = l_self[head];
        const float4 v = *reinterpret_cast<const float4*>(&h[(size_t)node * FDIM + f0]);
        acc = make_float4(a * v.x, a * v.y, a * v.z, a * v.w);
    }
    for (int e = 0; e < deg; ++e){
        int s = l_sidx[e];
        if (FILTER && s < 0) continue;
        float al = l_alph[e][head];
        const float4 u = *reinterpret_cast<const float4*>(&h[(size_t)s * FDIM + f0]);
        acc.x += al * u.x; acc.y += al * u.y; acc.z += al * u.z; acc.w += al * u.w;
    }
    const float4 b = *reinterpret_cast<const float4*>(&bias[f0]);
    float4 o = make_float4(elu(acc.x + b.x), elu(acc.y + b.y),
                           elu(acc.z + b.z), elu(acc.w + b.w));
    *reinterpret_cast<float4*>(&out[(size_t)node * FDIM + f0]) = o;
    // fused TopK pool score: half-dot -> LDS -> combine
    const float4 w = *reinterpret_cast<const float4*>(&pw[f0]);
    float s = o.x * w.x + o.y * w.y + o.z * w.z + o.w * w.w;
#pragma unroll
    for (int off = 32; off > 0; off >>= 1) s += __shfl_xor(s, off);
    if (lane == 0) sred[wv] = s;
    __syncthreads();
    if (threadIdx.x == 0)
        score[node] = tanhf((sred[0] + sred[1]) * (*invn));
}

// ---- exact top-k select (4x 8-bit radix) + compact, single block -----------
// Per-wave private histograms (16x256). Optionally (aux!=null) also zeros
// gsum[512]+done and computes invn=1/||w|| for the NEXT layer's pool.
__global__ __launch_bounds__(1024) void select_compact(const float* __restrict__ score,
        int n, int k, int* __restrict__ remap, int* __restrict__ oldidx,
        float* __restrict__ gsum, int* __restrict__ done,
        const float* __restrict__ w, float* __restrict__ invn)
{
    __shared__ unsigned hist[16][256];
    __shared__ unsigned s_prefix, s_rem, l_tie, l_keep;
    __shared__ float red2[16];
    int t = threadIdx.x;
    int wv = t >> 6;
    if (t == 0){ s_prefix = 0u; s_rem = (unsigned)k; l_tie = 0u; l_keep = 0u; }
    for (int i = t; i < 16 * 256; i += 1024) ((unsigned*)hist)[i] = 0u;
    __syncthreads();
    for (int pass = 3; pass >= 0; --pass){
        unsigned shift = (unsigned)pass * 8u;
        unsigned pmask = (pass == 3) ? 0u : (0xFFFFFFFFu << (shift + 8u));
        unsigned pref = s_prefix;
        for (int i = t; i < n; i += 1024){
            unsigned key = ordkey(score[i]);
            if ((key & pmask) == pref) atomicAdd(&hist[wv][(key >> shift) & 255u], 1u);
        }
        __syncthreads();
        if (t < 256){
            unsigned a = 0;
#pragma unroll
            for (int wq = 0; wq < 16; ++wq) a += hist[wq][t];
            hist[0][t] = a;
        }
        __syncthreads();
        if (t == 0){
            unsigned rem = s_rem, acc = 0, d = 255;
            for (;;){
                unsigned c = hist[0][d];
                if (acc + c >= rem) break;
                acc += c;
                if (d == 0) break;
                --d;
            }
            s_prefix = pref | (d << shift);
            s_rem = rem - acc;
        }
        __syncthreads();
        for (int i = t; i < 16 * 256; i += 1024) ((unsigned*)hist)[i] = 0u;
        __syncthreads();
    }
    unsigned T = s_prefix, ties = s_rem;
    for (int i = t; i < n; i += 1024){
        unsigned key = ordkey(score[i]);
        int keep = 0;
        if (key > T) keep = 1;
        else if (key == T){
            unsigned tk = atomicAdd(&l_tie, 1u);
            if (tk < ties) keep = 1;
        }
        if (keep){
            int pos = (int)atomicAdd(&l_keep, 1u);
            remap[i] = pos;
            oldidx[pos] = i;
        } else remap[i] = -1;
    }
    if (gsum){
        if (t < 512) gsum[t] = 0.f;
        if (t == 0) *done = 0;
        float s = (t < 512) ? w[t] * w[t] : 0.f;
#pragma unroll
        for (int off = 32; off > 0; off >>= 1) s += __shfl_xor(s, off);
        if ((t & 63) == 0) red2[wv] = s;
        __syncthreads();
        if (t == 0){
            float a = 0.f;
            for (int i = 0; i < 16; ++i) a += red2[i];
            *invn = rsqrtf(a);
        }
    }
}

// --------- readout: mean-pool reduce + final 512x10 GEMM (last block) -------
__global__ __launch_bounds__(512) void final_reduce(const float* __restrict__ x,
        const int* __restrict__ oldidx, const float* __restrict__ score, int k,
        float* __restrict__ gsum, int* __restrict__ done,
        const float* __restrict__ Wl, const float* __restrict__ bl,
        float* __restrict__ out)
{
    __shared__ float gsh[512];
    __shared__ int last;
    int t = threadIdx.x; // 512
    float a = 0.f;
    for (int j = blockIdx.x; j < k; j += gridDim.x){
        int o = oldidx[j];
        a += x[(size_t)o * FDIM + t] * score[o];
    }
    atomicAdd(&gsum[t], a);
    __threadfence();
    if (t == 0) last = (atomicAdd(done, 1) == (int)gridDim.x - 1);
    __syncthreads();
    if (!last) return;
    // last block: atomic reads give coherent view of all partial sums
    gsh[t] = atomicAdd(&gsum[t], 0.f);
    __syncthreads();
    int wv = t >> 6, lane = t & 63;
    for (int w = wv; w < 10; w += 8){
        float s = 0.f;
        for (int f = lane; f < FDIM; f += 64) s += gsh[f] * Wl[f * 10 + w];
#pragma unroll
        for (int off = 32; off > 0; off >>= 1) s += __shfl_xor(s, off);
        if (lane == 0) out[w] = s * (1.0f / K2_KEEP) + bl[w];
    }
}

extern "C" void kernel_launch(void* const* d_in, const int* in_sizes, int n_in,
                              void* d_out, int out_size, void* d_ws, size_t ws_size,
                              hipStream_t stream)
{
    (void)in_sizes; (void)n_in; (void)out_size; (void)ws_size;
    const float* x   = (const float*)d_in[0];
    const int*   ei  = (const int*)  d_in[1];
    const float* W1  = (const float*)d_in[3];
    const float* as1 = (const float*)d_in[4];
    const float* ad1 = (const float*)d_in[5];
    const float* b1  = (const float*)d_in[6];
    const float* pw1 = (const float*)d_in[7];
    const float* W2  = (const float*)d_in[8];
    const float* as2 = (const float*)d_in[9];
    const float* ad2 = (const float*)d_in[10];
    const float* b2  = (const float*)d_in[11];
    const float* pw2 = (const float*)d_in[12];
    const float* Wl  = (const float*)d_in[13];
    const float* bl  = (const float*)d_in[14];
    const int* src1 = ei;
    const int* dst1 = ei + E_EDGES;

    char* wsb = (char*)d_ws;
    size_t off = 0;
    auto alloc = [&](size_t bytes) -> char* {
        char* p = wsb + off;
        off += (bytes + 255) & ~(size_t)255;
        return p;
    };
    float* h1   = (float*)alloc((size_t)N_NODES * FDIM * 4);  // reused: h2 + out2
    float* out1 = (float*)alloc((size_t)N_NODES * FDIM * 4);
    float* asrc = (float*)alloc((size_t)N_NODES * NHEAD * 4);
    float* adst = (float*)alloc((size_t)N_NODES * NHEAD * 4);
    float* score= (float*)alloc((size_t)N_NODES * 4);
    float* invn = (float*)alloc(4);
    int* tmp  = (int*)alloc((size_t)N_NODES * 4);
    int* csr  = (int*)alloc((size_t)N_NODES * BSTRIDE * 4);
    int* remap= (int*)alloc((size_t)N_NODES * 4);
    int* oldi = (int*)alloc((size_t)K1_KEEP * 4);
    float* gsum = (float*)alloc(512 * 4);
    int* done = (int*)alloc(4);
    float* h2   = h1;                            // layer-2 aliases into h1 region
    float* out2 = h1 + (size_t)K1_KEEP * FDIM;   // N*F == 2*K1*F, fits exactly

    // ---- layer 1 (GAT on N nodes, E edges + self loops) ----
    int gx1 = (N_NODES + 63) / 64;
    clear_meta<<<(N_NODES + 255) / 256, 256, 0, stream>>>(tmp, N_NODES, pw1, invn);
    gemm_tile<64, 128, true, false><<<gx1 * 4, 256, 0, stream>>>(x, W1, h1, nullptr, nullptr,
                                                                 as1, ad1, asrc, adst, N_NODES);
    edge_fill<<<(E_EDGES + 255) / 256, 256, 0, stream>>>(src1, dst1, E_EDGES, tmp, csr);
    gat_fused<false><<<N_NODES, 128, 0, stream>>>(h1, asrc, adst, tmp, csr,
                                                  nullptr, nullptr, b1,
                                                  pw1, invn, out1, score, N_NODES);

    // ---- pool 1 (keep K1); also preps pw2-norm + gsum/done for readout ----
    select_compact<<<1, 1024, 0, stream>>>(score, N_NODES, K1_KEEP, remap, oldi,
                                           gsum, done, pw2, invn);

    // ---- layer 2 (GAT on K1 nodes; edges = L1 buckets filtered via remap) ----
    int gx2 = (K1_KEEP + 63) / 64;
    gemm_tile<512, 64, false, true><<<gx2 * 8, 256, 0, stream>>>(out1, W2, h2, oldi, score,
                                                                 nullptr, nullptr, nullptr, nullptr, K1_KEEP);
    attn_scores<<<K1_KEEP, 256, 0, stream>>>(h2, as2, ad2, asrc, adst, K1_KEEP);
    gat_fused<true><<<K1_KEEP, 128, 0, stream>>>(h2, asrc, adst, tmp, csr,
                                                 oldi, remap, b2,
                                                 pw2, invn, out2, score, K1_KEEP);

    // ---- pool 2 (keep K2) + fused readout ----
    select_compact<<<1, 1024, 0, stream>>>(score, K1_KEEP, K2_KEEP, remap, oldi,
                                           nullptr, nullptr, nullptr, nullptr);
    final_reduce<<<64, 512, 0, stream>>>(out2, oldi, score, K2_KEEP, gsum, done,
                                         Wl, bl, (float*)d_out);
}

// Round 13
// 484.587 us; speedup vs baseline: 1.0154x; 1.0154x over previous
//
#include <hip/hip_runtime.h>
#include <math.h>

#define N_NODES 20000
#define E_EDGES 200000
#define K1_KEEP 10000
#define K2_KEEP 5000
#define HIDC 128
#define NHEAD 4
#define FDIM 512   // NHEAD*HIDC
#define NEG 0.2f
#define BSTRIDE 64 // bucket CSR stride; P(deg>64)~e^-64 for Binom(200k,1/20k)

__device__ __forceinline__ float leaky(float x){ return x > 0.f ? x : NEG * x; }
__device__ __forceinline__ float elu(float x){ return x > 0.f ? x : expm1f(x); }
// monotone float->uint key (ascending)
__device__ __forceinline__ unsigned ordkey(float f){
    unsigned u = __float_as_uint(f);
    return (u & 0x80000000u) ? ~u : (u | 0x80000000u);
}

// ---------------- GEMM: out[n x 512] = A[n x K] @ W[K x 512] ----------------
// 64xCOLB tile / 256 threads / KC=32 LDS stage / 4x(COLB/16) per thread.
// r8-r12 lessons: COLB=64 w/ 1256 blocks is the plateau (~105us, VALU 43% =
// DS-issue cap); raising DS:FMA costs waves/CU and nets zero (r9); MR=8
// collapses occupancy (r7). Column layout {4tc,(+64)} -> 2-way LDS aliasing
// only (free on CDNA4).
// ATTN  (COLB=128): full attention dots in epilogue (col block == one head).
// ATTNA (COLB=64): HALF-dots, combined via atomicAdd — exactly 2 float
//   contributions per (node,head); a+b==b+a in IEEE -> replay-deterministic.
//   Requires asrc/adst pre-zeroed (done in select_compact #1).
// GATHER: A row r is gidx[r] scaled by gsc[gidx[r]] (TopK pool gather fused).
template<int K, int COLB, bool ATTN, bool ATTNA, bool GATHER>
__global__ __launch_bounds__(256) void gemm_tile(const float* __restrict__ A,
        const float* __restrict__ W, float* __restrict__ out,
        const int* __restrict__ gidx, const float* __restrict__ gsc,
        const float* __restrict__ avS, const float* __restrict__ avD,
        float* __restrict__ asrc, float* __restrict__ adst, int n)
{
    constexpr int NR = COLB / 16;        // 8 or 4 cols per thread
    constexpr int WPT = COLB / 32;       // W-stage float4s per thread (4 or 2)
    constexpr int BPR = 512 / COLB;      // col blocks per row stripe
    __shared__ float At[32][68];         // transposed A tile (16B-aligned rows)
    __shared__ float Wt[32][COLB];
    int t = threadIdx.x;
    int bid = blockIdx.x;
    int row0 = (bid / BPR) * 64;
    int col0 = (bid % BPR) * COLB;
    int tr = t >> 4;       // 0..15 -> rows 4*tr..4*tr+3
    int tc = t & 15;       // cols {col0+4tc.. (+64 for NR==8)}
    float acc[4][NR] = {};

    // loop-invariant row indirection for A staging
    int arow[2]; float asc[2];
#pragma unroll
    for (int i = 0; i < 2; ++i){
        int r = (t + i * 256) >> 3;
        int gr = row0 + r;
        arow[i] = -1; asc[i] = 1.f;
        if (gr < n){
            if (GATHER){ arow[i] = gidx[gr]; asc[i] = gsc[arow[i]]; }
            else arow[i] = gr;
        }
    }

    float4 pa[2], pw[WPT];
    // prefetch first tile
#pragma unroll
    for (int i = 0; i < 2; ++i){
        int kq = (t + i * 256) & 7;
        pa[i] = make_float4(0.f, 0.f, 0.f, 0.f);
        if (arow[i] >= 0){
            pa[i] = *reinterpret_cast<const float4*>(&A[(size_t)arow[i] * K + kq * 4]);
            if (GATHER){ pa[i].x *= asc[i]; pa[i].y *= asc[i]; pa[i].z *= asc[i]; pa[i].w *= asc[i]; }
        }
    }
#pragma unroll
    for (int i = 0; i < WPT; ++i){
        int s = t + i * 256; int k = s / (COLB / 4), c4 = s % (COLB / 4);
        pw[i] = *reinterpret_cast<const float4*>(&W[(size_t)k * 512 + col0 + c4 * 4]);
    }

    for (int kc = 0; kc < K; kc += 32){
        // write staged regs to LDS
#pragma unroll
        for (int i = 0; i < 2; ++i){
            int s = t + i * 256; int r = s >> 3, kq = s & 7;
            At[kq * 4 + 0][r] = pa[i].x;
            At[kq * 4 + 1][r] = pa[i].y;
            At[kq * 4 + 2][r] = pa[i].z;
            At[kq * 4 + 3][r] = pa[i].w;
        }
#pragma unroll
        for (int i = 0; i < WPT; ++i){
            int s = t + i * 256; int k = s / (COLB / 4), c4 = s % (COLB / 4);
            *reinterpret_cast<float4*>(&Wt[k][c4 * 4]) = pw[i];
        }
        __syncthreads();
        if (kc + 32 < K){   // prefetch next tile while computing this one
            int kn = kc + 32;
#pragma unroll
            for (int i = 0; i < 2; ++i){
                int kq = (t + i * 256) & 7;
                pa[i] = make_float4(0.f, 0.f, 0.f, 0.f);
                if (arow[i] >= 0){
                    pa[i] = *reinterpret_cast<const float4*>(&A[(size_t)arow[i] * K + kn + kq * 4]);
                    if (GATHER){ pa[i].x *= asc[i]; pa[i].y *= asc[i]; pa[i].z *= asc[i]; pa[i].w *= asc[i]; }
                }
            }
#pragma unroll
            for (int i = 0; i < WPT; ++i){
                int s = t + i * 256; int k = s / (COLB / 4), c4 = s % (COLB / 4);
                pw[i] = *reinterpret_cast<const float4*>(&W[(size_t)(kn + k) * 512 + col0 + c4 * 4]);
            }
        }
#pragma unroll 8
        for (int kk = 0; kk < 32; ++kk){
            float4 a = *reinterpret_cast<const float4*>(&At[kk][tr * 4]);
            float af[4] = {a.x, a.y, a.z, a.w};
            float wf[NR];
            {
                float4 w0 = *reinterpret_cast<const float4*>(&Wt[kk][tc * 4]);
                wf[0] = w0.x; wf[1] = w0.y; wf[2] = w0.z; wf[3] = w0.w;
                if constexpr (NR == 8){
                    float4 w1 = *reinterpret_cast<const float4*>(&Wt[kk][tc * 4 + 64]);
                    wf[4] = w1.x; wf[5] = w1.y; wf[6] = w1.z; wf[7] = w1.w;
                }
            }
#pragma unroll
            for (int r = 0; r < 4; ++r)
#pragma unroll
                for (int c = 0; c < NR; ++c) acc[r][c] += af[r] * wf[c];
        }
        __syncthreads();
    }
#pragma unroll
    for (int r = 0; r < 4; ++r){
        int gr = row0 + 4 * tr + r;
        if (gr < n){
            *reinterpret_cast<float4*>(&out[(size_t)gr * 512 + col0 + tc * 4]) =
                make_float4(acc[r][0], acc[r][1], acc[r][2], acc[r][3]);
            if constexpr (NR == 8)
                *reinterpret_cast<float4*>(&out[(size_t)gr * 512 + col0 + 64 + tc * 4]) =
                    make_float4(acc[r][4], acc[r][5], acc[r][6], acc[r][7]);
        }
    }
    if constexpr (ATTN){
        int head = col0 >> 7;
        const float* as = avS + head * HIDC;
        const float* ad = avD + head * HIDC;
#pragma unroll
        for (int r = 0; r < 4; ++r){
            float s = 0.f, d = 0.f;
#pragma unroll
            for (int c = 0; c < 4; ++c){
                s += acc[r][c] * as[4 * tc + c];
                d += acc[r][c] * ad[4 * tc + c];
                s += acc[r][4 + c] * as[64 + 4 * tc + c];
                d += acc[r][4 + c] * ad[64 + 4 * tc + c];
            }
#pragma unroll
            for (int off = 1; off < 16; off <<= 1){ s += __shfl_xor(s, off); d += __shfl_xor(d, off); }
            int gr = row0 + 4 * tr + r;
            if (tc == 0 && gr < n){ asrc[gr * 4 + head] = s; adst[gr * 4 + head] = d; }
        }
    }
    if constexpr (ATTNA){
        int head = col0 >> 7;
        int hoff = col0 & 127;             // 0 or 64: this block's half of the head
        const float* as = avS + head * HIDC + hoff;
        const float* ad = avD + head * HIDC + hoff;
#pragma unroll
        for (int r = 0; r < 4; ++r){
            float s = 0.f, d = 0.f;
#pragma unroll
            for (int c = 0; c < 4; ++c){
                s += acc[r][c] * as[4 * tc + c];
                d += acc[r][c] * ad[4 * tc + c];
            }
#pragma unroll
            for (int off = 1; off < 16; off <<= 1){ s += __shfl_xor(s, off); d += __shfl_xor(d, off); }
            int gr = row0 + 4 * tr + r;
            if (tc == 0 && gr < n){
                atomicAdd(&asrc[gr * 4 + head], s);
                atomicAdd(&adst[gr * 4 + head], d);
            }
        }
    }
}

// ---------------- meta clear + pool-weight norm (block 0) -------------------
__global__ __launch_bounds__(256) void clear_meta(int* __restrict__ tmp, int n,
        const float* __restrict__ w, float* __restrict__ invn){
    __shared__ float red[4];
    int i = blockIdx.x * 256 + threadIdx.x;
    if (i < n) tmp[i] = 0;
    if (blockIdx.x == 0){
        int t = threadIdx.x;
        float s = w[t] * w[t] + w[t + 256] * w[t + 256];
#pragma unroll
        for (int off = 32; off > 0; off >>= 1) s += __shfl_xor(s, off);
        if ((t & 63) == 0) red[t >> 6] = s;
        __syncthreads();
        if (t == 0) *invn = rsqrtf(red[0] + red[1] + red[2] + red[3]);
    }
}

// bucketed CSR fill: no count/scan passes needed; tmp returns degrees.
__global__ void edge_fill(const int* __restrict__ src, const int* __restrict__ dst, int e,
                          int* __restrict__ tmp, int* __restrict__ csr){
    int i = blockIdx.x * 256 + threadIdx.x;
    if (i >= e) return;
    int d = dst[i];
    int pos = atomicAdd(&tmp[d], 1);
    if (pos < BSTRIDE) csr[d * BSTRIDE + pos] = src[i];
}

// ---- fused softmax-stats + aggregation + pool score, one wave per node -----
// r10 form — r11 (2 waves/node) and r12 (stats->LDS + 2-wave agg) both lost:
// duplicated/serialized stats and idle waves outweigh the shorter gather
// chain. Phase mapping lane=(e*4+h) for stats; lane->8 features for agg;
// alpha via __shfl bcast; sequential inner loop (r9: padded unrolls lose).
// FILTER: walk LAYER-1 bucket row of oldi[node]; keep srcs with remap>=0
// (exact: removed edges contribute exp->0 in the reference).
template<bool FILTER>
__global__ __launch_bounds__(256) void gat_fused(const float* __restrict__ h,
        const float* __restrict__ asrc, const float* __restrict__ adst,
        const int* __restrict__ degs, const int* __restrict__ csr,
        const int* __restrict__ oldi, const int* __restrict__ remap,
        const float* __restrict__ bias, const float* __restrict__ pw,
        const float* __restrict__ invn, float* __restrict__ out,
        float* __restrict__ score, int n)
{
    int node = blockIdx.x * 4 + (threadIdx.x >> 6);
    int lane = threadIdx.x & 63;
    if (node >= n) return;
    int od = FILTER ? oldi[node] : node;
    int deg = degs[od]; if (deg > BSTRIDE) deg = BSTRIDE;
    int e0 = od * BSTRIDE, e1 = e0 + deg;
    int ph = lane & 3;
    int pe = lane >> 2;
    float adn  = adst[node * 4 + ph];
    float slog = leaky(asrc[node * 4 + ph] + adn);
    float mx = slog;
    for (int j = e0 + pe; j < e1; j += 16){
        int s = csr[j];
        if (FILTER){ s = remap[s]; if (s < 0) continue; }
        mx = fmaxf(mx, leaky(asrc[s * 4 + ph] + adn));
    }
#pragma unroll
    for (int off = 4; off < 64; off <<= 1) mx = fmaxf(mx, __shfl_xor(mx, off));
    float lsum = 0.f;
    for (int j = e0 + pe; j < e1; j += 16){
        int s = csr[j];
        if (FILTER){ s = remap[s]; if (s < 0) continue; }
        lsum += expf(leaky(asrc[s * 4 + ph] + adn) - mx);
    }
#pragma unroll
    for (int off = 4; off < 64; off <<= 1) lsum += __shfl_xor(lsum, off);
    float es  = expf(slog - mx);
    float inv = 1.f / (lsum + es);

    int f0 = lane * 8;
    int hf = lane >> 4;
    float aself = __shfl(es * inv, hf);  // stats lane (pe=0,ph=hf) == lane hf
    float4 acc0, acc1;
    {
        const float4* hp = reinterpret_cast<const float4*>(&h[(size_t)node * FDIM + f0]);
        float4 v0 = hp[0], v1 = hp[1];
        acc0 = make_float4(aself * v0.x, aself * v0.y, aself * v0.z, aself * v0.w);
        acc1 = make_float4(aself * v1.x, aself * v1.y, aself * v1.z, aself * v1.w);
    }
    for (int base = e0; base < e1; base += 16){
        int cnt = e1 - base; if (cnt > 16) cnt = 16;
        float alpha = 0.f; int sidx = -1;
        if (pe < cnt){
            int s = csr[base + pe];
            if (FILTER) s = remap[s];
            if (s >= 0){
                sidx = s;
                alpha = expf(leaky(asrc[s * 4 + ph] + adn) - mx) * inv;
            }
        }
        for (int e = 0; e < cnt; ++e){
            int s = __shfl(sidx, e * 4);
            if (FILTER && s < 0) continue;
            float al = __shfl(alpha, e * 4 + hf);
            const float4* p = reinterpret_cast<const float4*>(&h[(size_t)s * FDIM + f0]);
            float4 u0 = p[0], u1 = p[1];
            acc0.x += al * u0.x; acc0.y += al * u0.y; acc0.z += al * u0.z; acc0.w += al * u0.w;
            acc1.x += al * u1.x; acc1.y += al * u1.y; acc1.z += al * u1.z; acc1.w += al * u1.w;
        }
    }
    const float4* bp = reinterpret_cast<const float4*>(&bias[f0]);
    float4 b0 = bp[0], b1 = bp[1];
    float4 o0 = make_float4(elu(acc0.x + b0.x), elu(acc0.y + b0.y),
                            elu(acc0.z + b0.z), elu(acc0.w + b0.w));
    float4 o1 = make_float4(elu(acc1.x + b1.x), elu(acc1.y + b1.y),
                            elu(acc1.z + b1.z), elu(acc1.w + b1.w));
    float4* op = reinterpret_cast<float4*>(&out[(size_t)node * FDIM + f0]);
    op[0] = o0; op[1] = o1;
    // fused TopK pool score
    const float4* wp = reinterpret_cast<const float4*>(&pw[f0]);
    float4 w0 = wp[0], w1 = wp[1];
    float s = o0.x * w0.x + o0.y * w0.y + o0.z * w0.z + o0.w * w0.w
            + o1.x * w1.x + o1.y * w1.y + o1.z * w1.z + o1.w * w1.w;
#pragma unroll
    for (int off = 32; off > 0; off >>= 1) s += __shfl_xor(s, off);
    if (lane == 0) score[node] = tanhf(s * (*invn));
}

// ---- exact top-k select (4x 8-bit radix) + compact, single block -----------
// Per-wave private histograms (16x256). When aux!=null also: zero gsum+done,
// compute invn=1/||w|| for next pool, and zero asrc/adst (za floats) for the
// GEMM2 atomic attention epilogue.
__global__ __launch_bounds__(1024) void select_compact(const float* __restrict__ score,
        int n, int k, int* __restrict__ remap, int* __restrict__ oldidx,
        float* __restrict__ gsum, int* __restrict__ done,
        const float* __restrict__ w, float* __restrict__ invn,
        float* __restrict__ zasrc, float* __restrict__ zadst, int za)
{
    __shared__ unsigned hist[16][256];
    __shared__ unsigned s_prefix, s_rem, l_tie, l_keep;
    __shared__ float red2[16];
    int t = threadIdx.x;
    int wv = t >> 6;
    if (t == 0){ s_prefix = 0u; s_rem = (unsigned)k; l_tie = 0u; l_keep = 0u; }
    for (int i = t; i < 16 * 256; i += 1024) ((unsigned*)hist)[i] = 0u;
    __syncthreads();
    for (int pass = 3; pass >= 0; --pass){
        unsigned shift = (unsigned)pass * 8u;
        unsigned pmask = (pass == 3) ? 0u : (0xFFFFFFFFu << (shift + 8u));
        unsigned pref = s_prefix;
        for (int i = t; i < n; i += 1024){
            unsigned key = ordkey(score[i]);
            if ((key & pmask) == pref) atomicAdd(&hist[wv][(key >> shift) & 255u], 1u);
        }
        __syncthreads();
        if (t < 256){
            unsigned a = 0;
#pragma unroll
            for (int wq = 0; wq < 16; ++wq) a += hist[wq][t];
            hist[0][t] = a;
        }
        __syncthreads();
        if (t == 0){
            unsigned rem = s_rem, acc = 0, d = 255;
            for (;;){
                unsigned c = hist[0][d];
                if (acc + c >= rem) break;
                acc += c;
                if (d == 0) break;
                --d;
            }
            s_prefix = pref | (d << shift);
            s_rem = rem - acc;
        }
        __syncthreads();
        for (int i = t; i < 16 * 256; i += 1024) ((unsigned*)hist)[i] = 0u;
        __syncthreads();
    }
    unsigned T = s_prefix, ties = s_rem;
    for (int i = t; i < n; i += 1024){
        unsigned key = ordkey(score[i]);
        int keep = 0;
        if (key > T) keep = 1;
        else if (key == T){
            unsigned tk = atomicAdd(&l_tie, 1u);
            if (tk < ties) keep = 1;
        }
        if (keep){
            int pos = (int)atomicAdd(&l_keep, 1u);
            remap[i] = pos;
            oldidx[pos] = i;
        } else remap[i] = -1;
    }
    if (gsum){
        if (t < 512) gsum[t] = 0.f;
        if (t == 0) *done = 0;
        for (int i = t; i < za; i += 1024){ zasrc[i] = 0.f; zadst[i] = 0.f; }
        float s = (t < 512) ? w[t] * w[t] : 0.f;
#pragma unroll
        for (int off = 32; off > 0; off >>= 1) s += __shfl_xor(s, off);
        if ((t & 63) == 0) red2[wv] = s;
        __syncthreads();
        if (t == 0){
            float a = 0.f;
            for (int i = 0; i < 16; ++i) a += red2[i];
            *invn = rsqrtf(a);
        }
    }
}

// --------- readout: mean-pool reduce + final 512x10 GEMM (last block) -------
__global__ __launch_bounds__(512) void final_reduce(const float* __restrict__ x,
        const int* __restrict__ oldidx, const float* __restrict__ score, int k,
        float* __restrict__ gsum, int* __restrict__ done,
        const float* __restrict__ Wl, const float* __restrict__ bl,
        float* __restrict__ out)
{
    __shared__ float gsh[512];
    __shared__ int last;
    int t = threadIdx.x; // 512
    float a = 0.f;
    for (int j = blockIdx.x; j < k; j += gridDim.x){
        int o = oldidx[j];
        a += x[(size_t)o * FDIM + t] * score[o];
    }
    atomicAdd(&gsum[t], a);
    __threadfence();
    if (t == 0) last = (atomicAdd(done, 1) == (int)gridDim.x - 1);
    __syncthreads();
    if (!last) return;
    // last block: atomic reads give coherent view of all partial sums
    gsh[t] = atomicAdd(&gsum[t], 0.f);
    __syncthreads();
    int wv = t >> 6, lane = t & 63;
    for (int w = wv; w < 10; w += 8){
        float s = 0.f;
        for (int f = lane; f < FDIM; f += 64) s += gsh[f] * Wl[f * 10 + w];
#pragma unroll
        for (int off = 32; off > 0; off >>= 1) s += __shfl_xor(s, off);
        if (lane == 0) out[w] = s * (1.0f / K2_KEEP) + bl[w];
    }
}

extern "C" void kernel_launch(void* const* d_in, const int* in_sizes, int n_in,
                              void* d_out, int out_size, void* d_ws, size_t ws_size,
                              hipStream_t stream)
{
    (void)in_sizes; (void)n_in; (void)out_size; (void)ws_size;
    const float* x   = (const float*)d_in[0];
    const int*   ei  = (const int*)  d_in[1];
    const float* W1  = (const float*)d_in[3];
    const float* as1 = (const float*)d_in[4];
    const float* ad1 = (const float*)d_in[5];
    const float* b1  = (const float*)d_in[6];
    const float* pw1 = (const float*)d_in[7];
    const float* W2  = (const float*)d_in[8];
    const float* as2 = (const float*)d_in[9];
    const float* ad2 = (const float*)d_in[10];
    const float* b2  = (const float*)d_in[11];
    const float* pw2 = (const float*)d_in[12];
    const float* Wl  = (const float*)d_in[13];
    const float* bl  = (const float*)d_in[14];
    const int* src1 = ei;
    const int* dst1 = ei + E_EDGES;

    char* wsb = (char*)d_ws;
    size_t off = 0;
    auto alloc = [&](size_t bytes) -> char* {
        char* p = wsb + off;
        off += (bytes + 255) & ~(size_t)255;
        return p;
    };
    float* h1   = (float*)alloc((size_t)N_NODES * FDIM * 4);  // reused: h2 + out2
    float* out1 = (float*)alloc((size_t)N_NODES * FDIM * 4);
    float* asrc = (float*)alloc((size_t)N_NODES * NHEAD * 4);
    float* adst = (float*)alloc((size_t)N_NODES * NHEAD * 4);
    float* score= (float*)alloc((size_t)N_NODES * 4);
    float* invn = (float*)alloc(4);
    int* tmp  = (int*)alloc((size_t)N_NODES * 4);
    int* csr  = (int*)alloc((size_t)N_NODES * BSTRIDE * 4);
    int* remap= (int*)alloc((size_t)N_NODES * 4);
    int* oldi = (int*)alloc((size_t)K1_KEEP * 4);
    float* gsum = (float*)alloc(512 * 4);
    int* done = (int*)alloc(4);
    float* h2   = h1;                            // layer-2 aliases into h1 region
    float* out2 = h1 + (size_t)K1_KEEP * FDIM;   // N*F == 2*K1*F, fits exactly

    // ---- layer 1 (GAT on N nodes, E edges + self loops) ----
    int gx1 = (N_NODES + 63) / 64;
    clear_meta<<<(N_NODES + 255) / 256, 256, 0, stream>>>(tmp, N_NODES, pw1, invn);
    gemm_tile<64, 128, true, false, false><<<gx1 * 4, 256, 0, stream>>>(x, W1, h1,
            nullptr, nullptr, as1, ad1, asrc, adst, N_NODES);
    edge_fill<<<(E_EDGES + 255) / 256, 256, 0, stream>>>(src1, dst1, E_EDGES, tmp, csr);
    gat_fused<false><<<(N_NODES + 3) / 4, 256, 0, stream>>>(h1, asrc, adst, tmp, csr,
            nullptr, nullptr, b1, pw1, invn, out1, score, N_NODES);

    // ---- pool 1; also preps pw2-norm, gsum/done, zeroed asrc/adst ----
    select_compact<<<1, 1024, 0, stream>>>(score, N_NODES, K1_KEEP, remap, oldi,
                                           gsum, done, pw2, invn,
                                           asrc, adst, K1_KEEP * NHEAD);

    // ---- layer 2 (GAT on K1 nodes; edges = L1 buckets filtered via remap) ----
    int gx2 = (K1_KEEP + 63) / 64;
    gemm_tile<512, 64, false, true, true><<<gx2 * 8, 256, 0, stream>>>(out1, W2, h2,
            oldi, score, as2, ad2, asrc, adst, K1_KEEP);
    gat_fused<true><<<(K1_KEEP + 3) / 4, 256, 0, stream>>>(h2, asrc, adst, tmp, csr,
            oldi, remap, b2, pw2, invn, out2, score, K1_KEEP);

    // ---- pool 2 + fused readout ----
    select_compact<<<1, 1024, 0, stream>>>(score, K1_KEEP, K2_KEEP, remap, oldi,
                                           nullptr, nullptr, nullptr, nullptr,
                                           nullptr, nullptr, 0);
    final_reduce<<<64, 512, 0, stream>>>(out2, oldi, score, K2_KEEP, gsum, done,
                                         Wl, bl, (float*)d_out);
}

// Round 14
// 475.398 us; speedup vs baseline: 1.0350x; 1.0193x over previous
//
#include <hip/hip_runtime.h>
#include <math.h>

#define N_NODES 20000
#define E_EDGES 200000
#define K1_KEEP 10000
#define K2_KEEP 5000
#define HIDC 128
#define NHEAD 4
#define FDIM 512   // NHEAD*HIDC
#define NEG 0.2f
#define BSTRIDE 64 // bucket CSR stride; P(deg>64)~e^-64 for Binom(200k,1/20k)
#define SELCAP 20  // keys/thread in select (1024*20 >= 20000)

__device__ __forceinline__ float leaky(float x){ return x > 0.f ? x : NEG * x; }
__device__ __forceinline__ float elu(float x){ return x > 0.f ? x : expm1f(x); }
// monotone float->uint key (ascending)
__device__ __forceinline__ unsigned ordkey(float f){
    unsigned u = __float_as_uint(f);
    return (u & 0x80000000u) ? ~u : (u | 0x80000000u);
}

// ---------------- GEMM: out[n x 512] = A[n x K] @ W[K x 512] ----------------
// 64xCOLB tile / 256 threads / KC=32 LDS stage / 4x(COLB/16) per thread.
// r8-r13 lessons: COLB=64 w/ 1256 blocks is the plateau (~105us, VALU 43% =
// DS-issue cap); raising DS:FMA costs waves/CU and nets zero (r9); MR=8
// collapses occupancy (r7); atomic half-dot attention epilogue slows the
// GEMM more than it saves (r13). Column layout {4tc,(+64)} -> 2-way LDS
// aliasing only (free on CDNA4).
// ATTN (COLB=128 only): fused per-row attention dots (col block == one head).
// GATHER: A row r is gidx[r] scaled by gsc[gidx[r]] (TopK pool gather fused).
template<int K, int COLB, bool ATTN, bool GATHER>
__global__ __launch_bounds__(256) void gemm_tile(const float* __restrict__ A,
        const float* __restrict__ W, float* __restrict__ out,
        const int* __restrict__ gidx, const float* __restrict__ gsc,
        const float* __restrict__ avS, const float* __restrict__ avD,
        float* __restrict__ asrc, float* __restrict__ adst, int n)
{
    constexpr int NR = COLB / 16;        // 8 or 4 cols per thread
    constexpr int WPT = COLB / 32;       // W-stage float4s per thread (4 or 2)
    constexpr int BPR = 512 / COLB;      // col blocks per row stripe
    __shared__ float At[32][68];         // transposed A tile (16B-aligned rows)
    __shared__ float Wt[32][COLB];
    int t = threadIdx.x;
    int bid = blockIdx.x;
    int row0 = (bid / BPR) * 64;
    int col0 = (bid % BPR) * COLB;
    int tr = t >> 4;       // 0..15 -> rows 4*tr..4*tr+3
    int tc = t & 15;       // cols {col0+4tc.. (+64 for NR==8)}
    float acc[4][NR] = {};

    // loop-invariant row indirection for A staging
    int arow[2]; float asc[2];
#pragma unroll
    for (int i = 0; i < 2; ++i){
        int r = (t + i * 256) >> 3;
        int gr = row0 + r;
        arow[i] = -1; asc[i] = 1.f;
        if (gr < n){
            if (GATHER){ arow[i] = gidx[gr]; asc[i] = gsc[arow[i]]; }
            else arow[i] = gr;
        }
    }

    float4 pa[2], pw[WPT];
    // prefetch first tile
#pragma unroll
    for (int i = 0; i < 2; ++i){
        int kq = (t + i * 256) & 7;
        pa[i] = make_float4(0.f, 0.f, 0.f, 0.f);
        if (arow[i] >= 0){
            pa[i] = *reinterpret_cast<const float4*>(&A[(size_t)arow[i] * K + kq * 4]);
            if (GATHER){ pa[i].x *= asc[i]; pa[i].y *= asc[i]; pa[i].z *= asc[i]; pa[i].w *= asc[i]; }
        }
    }
#pragma unroll
    for (int i = 0; i < WPT; ++i){
        int s = t + i * 256; int k = s / (COLB / 4), c4 = s % (COLB / 4);
        pw[i] = *reinterpret_cast<const float4*>(&W[(size_t)k * 512 + col0 + c4 * 4]);
    }

    for (int kc = 0; kc < K; kc += 32){
        // write staged regs to LDS
#pragma unroll
        for (int i = 0; i < 2; ++i){
            int s = t + i * 256; int r = s >> 3, kq = s & 7;
            At[kq * 4 + 0][r] = pa[i].x;
            At[kq * 4 + 1][r] = pa[i].y;
            At[kq * 4 + 2][r] = pa[i].z;
            At[kq * 4 + 3][r] = pa[i].w;
        }
#pragma unroll
        for (int i = 0; i < WPT; ++i){
            int s = t + i * 256; int k = s / (COLB / 4), c4 = s % (COLB / 4);
            *reinterpret_cast<float4*>(&Wt[k][c4 * 4]) = pw[i];
        }
        __syncthreads();
        if (kc + 32 < K){   // prefetch next tile while computing this one
            int kn = kc + 32;
#pragma unroll
            for (int i = 0; i < 2; ++i){
                int kq = (t + i * 256) & 7;
                pa[i] = make_float4(0.f, 0.f, 0.f, 0.f);
                if (arow[i] >= 0){
                    pa[i] = *reinterpret_cast<const float4*>(&A[(size_t)arow[i] * K + kn + kq * 4]);
                    if (GATHER){ pa[i].x *= asc[i]; pa[i].y *= asc[i]; pa[i].z *= asc[i]; pa[i].w *= asc[i]; }
                }
            }
#pragma unroll
            for (int i = 0; i < WPT; ++i){
                int s = t + i * 256; int k = s / (COLB / 4), c4 = s % (COLB / 4);
                pw[i] = *reinterpret_cast<const float4*>(&W[(size_t)(kn + k) * 512 + col0 + c4 * 4]);
            }
        }
#pragma unroll 8
        for (int kk = 0; kk < 32; ++kk){
            float4 a = *reinterpret_cast<const float4*>(&At[kk][tr * 4]);
            float af[4] = {a.x, a.y, a.z, a.w};
            float wf[NR];
            {
                float4 w0 = *reinterpret_cast<const float4*>(&Wt[kk][tc * 4]);
                wf[0] = w0.x; wf[1] = w0.y; wf[2] = w0.z; wf[3] = w0.w;
                if constexpr (NR == 8){
                    float4 w1 = *reinterpret_cast<const float4*>(&Wt[kk][tc * 4 + 64]);
                    wf[4] = w1.x; wf[5] = w1.y; wf[6] = w1.z; wf[7] = w1.w;
                }
            }
#pragma unroll
            for (int r = 0; r < 4; ++r)
#pragma unroll
                for (int c = 0; c < NR; ++c) acc[r][c] += af[r] * wf[c];
        }
        __syncthreads();
    }
#pragma unroll
    for (int r = 0; r < 4; ++r){
        int gr = row0 + 4 * tr + r;
        if (gr < n){
            *reinterpret_cast<float4*>(&out[(size_t)gr * 512 + col0 + tc * 4]) =
                make_float4(acc[r][0], acc[r][1], acc[r][2], acc[r][3]);
            if constexpr (NR == 8)
                *reinterpret_cast<float4*>(&out[(size_t)gr * 512 + col0 + 64 + tc * 4]) =
                    make_float4(acc[r][4], acc[r][5], acc[r][6], acc[r][7]);
        }
    }
    if constexpr (ATTN){
        int head = col0 >> 7;
        const float* as = avS + head * HIDC;
        const float* ad = avD + head * HIDC;
#pragma unroll
        for (int r = 0; r < 4; ++r){
            float s = 0.f, d = 0.f;
#pragma unroll
            for (int c = 0; c < 4; ++c){
                s += acc[r][c] * as[4 * tc + c];
                d += acc[r][c] * ad[4 * tc + c];
                s += acc[r][4 + c] * as[64 + 4 * tc + c];
                d += acc[r][4 + c] * ad[64 + 4 * tc + c];
            }
#pragma unroll
            for (int off = 1; off < 16; off <<= 1){ s += __shfl_xor(s, off); d += __shfl_xor(d, off); }
            int gr = row0 + 4 * tr + r;
            if (tc == 0 && gr < n){ asrc[gr * 4 + head] = s; adst[gr * 4 + head] = d; }
        }
    }
}

// ------------- attention scores: asrc[n][h], adst[n][h] ---------------------
__global__ __launch_bounds__(256) void attn_scores(const float* __restrict__ h,
        const float* __restrict__ a_src, const float* __restrict__ a_dst,
        float* __restrict__ asrc, float* __restrict__ adst, int n)
{
    int g = blockIdx.x * 4 + (threadIdx.x >> 6);
    int lane = threadIdx.x & 63;
    int node = g >> 2, head = g & 3;
    if (node >= n) return;
    const float* hp = h + (size_t)node * FDIM + head * HIDC;
    float v0 = hp[lane], v1 = hp[lane + 64];
    const float* as = a_src + head * HIDC;
    const float* ad = a_dst + head * HIDC;
    float s = v0 * as[lane] + v1 * as[lane + 64];
    float d = v0 * ad[lane] + v1 * ad[lane + 64];
#pragma unroll
    for (int off = 32; off > 0; off >>= 1){ s += __shfl_xor(s, off); d += __shfl_xor(d, off); }
    if (lane == 0){ asrc[node * 4 + head] = s; adst[node * 4 + head] = d; }
}

// ---------------- meta clear + pool-weight norm (block 0) -------------------
__global__ __launch_bounds__(256) void clear_meta(int* __restrict__ tmp, int n,
        const float* __restrict__ w, float* __restrict__ invn){
    __shared__ float red[4];
    int i = blockIdx.x * 256 + threadIdx.x;
    if (i < n) tmp[i] = 0;
    if (blockIdx.x == 0){
        int t = threadIdx.x;
        float s = w[t] * w[t] + w[t + 256] * w[t + 256];
#pragma unroll
        for (int off = 32; off > 0; off >>= 1) s += __shfl_xor(s, off);
        if ((t & 63) == 0) red[t >> 6] = s;
        __syncthreads();
        if (t == 0) *invn = rsqrtf(red[0] + red[1] + red[2] + red[3]);
    }
}

// bucketed CSR fill: no count/scan passes needed; tmp returns degrees.
__global__ void edge_fill(const int* __restrict__ src, const int* __restrict__ dst, int e,
                          int* __restrict__ tmp, int* __restrict__ csr){
    int i = blockIdx.x * 256 + threadIdx.x;
    if (i >= e) return;
    int d = dst[i];
    int pos = atomicAdd(&tmp[d], 1);
    if (pos < BSTRIDE) csr[d * BSTRIDE + pos] = src[i];
}

// ---- fused softmax-stats + aggregation + pool score, one wave per node -----
// r10 form — r11 (2 waves/node), r12 (stats->LDS + 2-wave agg), r13 (atomic
// attention epilogue) all lost. Phase mapping lane=(e*4+h) for stats;
// lane->8 features for agg; alpha via __shfl bcast; sequential inner loop.
// FILTER: walk LAYER-1 bucket row of oldi[node]; keep srcs with remap>=0
// (exact: removed edges contribute exp->0 in the reference).
template<bool FILTER>
__global__ __launch_bounds__(256) void gat_fused(const float* __restrict__ h,
        const float* __restrict__ asrc, const float* __restrict__ adst,
        const int* __restrict__ degs, const int* __restrict__ csr,
        const int* __restrict__ oldi, const int* __restrict__ remap,
        const float* __restrict__ bias, const float* __restrict__ pw,
        const float* __restrict__ invn, float* __restrict__ out,
        float* __restrict__ score, int n)
{
    int node = blockIdx.x * 4 + (threadIdx.x >> 6);
    int lane = threadIdx.x & 63;
    if (node >= n) return;
    int od = FILTER ? oldi[node] : node;
    int deg = degs[od]; if (deg > BSTRIDE) deg = BSTRIDE;
    int e0 = od * BSTRIDE, e1 = e0 + deg;
    int ph = lane & 3;
    int pe = lane >> 2;
    float adn  = adst[node * 4 + ph];
    float slog = leaky(asrc[node * 4 + ph] + adn);
    float mx = slog;
    for (int j = e0 + pe; j < e1; j += 16){
        int s = csr[j];
        if (FILTER){ s = remap[s]; if (s < 0) continue; }
        mx = fmaxf(mx, leaky(asrc[s * 4 + ph] + adn));
    }
#pragma unroll
    for (int off = 4; off < 64; off <<= 1) mx = fmaxf(mx, __shfl_xor(mx, off));
    float lsum = 0.f;
    for (int j = e0 + pe; j < e1; j += 16){
        int s = csr[j];
        if (FILTER){ s = remap[s]; if (s < 0) continue; }
        lsum += expf(leaky(asrc[s * 4 + ph] + adn) - mx);
    }
#pragma unroll
    for (int off = 4; off < 64; off <<= 1) lsum += __shfl_xor(lsum, off);
    float es  = expf(slog - mx);
    float inv = 1.f / (lsum + es);

    int f0 = lane * 8;
    int hf = lane >> 4;
    float aself = __shfl(es * inv, hf);  // stats lane (pe=0,ph=hf) == lane hf
    float4 acc0, acc1;
    {
        const float4* hp = reinterpret_cast<const float4*>(&h[(size_t)node * FDIM + f0]);
        float4 v0 = hp[0], v1 = hp[1];
        acc0 = make_float4(aself * v0.x, aself * v0.y, aself * v0.z, aself * v0.w);
        acc1 = make_float4(aself * v1.x, aself * v1.y, aself * v1.z, aself * v1.w);
    }
    for (int base = e0; base < e1; base += 16){
        int cnt = e1 - base; if (cnt > 16) cnt = 16;
        float alpha = 0.f; int sidx = -1;
        if (pe < cnt){
            int s = csr[base + pe];
            if (FILTER) s = remap[s];
            if (s >= 0){
                sidx = s;
                alpha = expf(leaky(asrc[s * 4 + ph] + adn) - mx) * inv;
            }
        }
        for (int e = 0; e < cnt; ++e){
            int s = __shfl(sidx, e * 4);
            if (FILTER && s < 0) continue;
            float al = __shfl(alpha, e * 4 + hf);
            const float4* p = reinterpret_cast<const float4*>(&h[(size_t)s * FDIM + f0]);
            float4 u0 = p[0], u1 = p[1];
            acc0.x += al * u0.x; acc0.y += al * u0.y; acc0.z += al * u0.z; acc0.w += al * u0.w;
            acc1.x += al * u1.x; acc1.y += al * u1.y; acc1.z += al * u1.z; acc1.w += al * u1.w;
        }
    }
    const float4* bp = reinterpret_cast<const float4*>(&bias[f0]);
    float4 b0 = bp[0], b1 = bp[1];
    float4 o0 = make_float4(elu(acc0.x + b0.x), elu(acc0.y + b0.y),
                            elu(acc0.z + b0.z), elu(acc0.w + b0.w));
    float4 o1 = make_float4(elu(acc1.x + b1.x), elu(acc1.y + b1.y),
                            elu(acc1.z + b1.z), elu(acc1.w + b1.w));
    float4* op = reinterpret_cast<float4*>(&out[(size_t)node * FDIM + f0]);
    op[0] = o0; op[1] = o1;
    // fused TopK pool score
    const float4* wp = reinterpret_cast<const float4*>(&pw[f0]);
    float4 w0 = wp[0], w1 = wp[1];
    float s = o0.x * w0.x + o0.y * w0.y + o0.z * w0.z + o0.w * w0.w
            + o1.x * w1.x + o1.y * w1.y + o1.z * w1.z + o1.w * w1.w;
#pragma unroll
    for (int off = 32; off > 0; off >>= 1) s += __shfl_xor(s, off);
    if (lane == 0) score[node] = tanhf(s * (*invn));
}

// ---- exact top-k select (4x 8-bit radix) + compact, single block -----------
// r14: keys staged ONCE into registers (statically-indexed unrolled array,
// SELCAP=20/thread) — 1 global pass instead of 5. Per-wave private LDS
// histograms. When gsum!=null also: zero gsum+done and compute invn=1/||w||
// for the next layer's pool (saves clear_meta #2).
__global__ __launch_bounds__(1024) void select_compact(const float* __restrict__ score,
        int n, int k, int* __restrict__ remap, int* __restrict__ oldidx,
        float* __restrict__ gsum, int* __restrict__ done,
        const float* __restrict__ w, float* __restrict__ invn)
{
    __shared__ unsigned hist[16][256];
    __shared__ unsigned s_prefix, s_rem, l_tie, l_keep;
    __shared__ float red2[16];
    int t = threadIdx.x;
    int wv = t >> 6;
    unsigned keys[SELCAP];
#pragma unroll
    for (int j = 0; j < SELCAP; ++j){
        int i = t + j * 1024;
        keys[j] = (i < n) ? ordkey(score[i]) : 0u;
    }
    if (t == 0){ s_prefix = 0u; s_rem = (unsigned)k; l_tie = 0u; l_keep = 0u; }
    for (int i = t; i < 16 * 256; i += 1024) ((unsigned*)hist)[i] = 0u;
    __syncthreads();
    for (int pass = 3; pass >= 0; --pass){
        unsigned shift = (unsigned)pass * 8u;
        unsigned pmask = (pass == 3) ? 0u : (0xFFFFFFFFu << (shift + 8u));
        unsigned pref = s_prefix;
#pragma unroll
        for (int j = 0; j < SELCAP; ++j){
            int i = t + j * 1024;
            if (i < n && (keys[j] & pmask) == pref)
                atomicAdd(&hist[wv][(keys[j] >> shift) & 255u], 1u);
        }
        __syncthreads();
        if (t < 256){
            unsigned a = 0;
#pragma unroll
            for (int wq = 0; wq < 16; ++wq) a += hist[wq][t];
            hist[0][t] = a;
        }
        __syncthreads();
        if (t == 0){
            unsigned rem = s_rem, acc = 0, d = 255;
            for (;;){
                unsigned c = hist[0][d];
                if (acc + c >= rem) break;
                acc += c;
                if (d == 0) break;
                --d;
            }
            s_prefix = pref | (d << shift);
            s_rem = rem - acc;
        }
        __syncthreads();
        for (int i = t; i < 16 * 256; i += 1024) ((unsigned*)hist)[i] = 0u;
        __syncthreads();
    }
    unsigned T = s_prefix, ties = s_rem;
#pragma unroll
    for (int j = 0; j < SELCAP; ++j){
        int i = t + j * 1024;
        if (i >= n) continue;
        unsigned key = keys[j];
        int keep = 0;
        if (key > T) keep = 1;
        else if (key == T){
            unsigned tk = atomicAdd(&l_tie, 1u);
            if (tk < ties) keep = 1;
        }
        if (keep){
            int pos = (int)atomicAdd(&l_keep, 1u);
            remap[i] = pos;
            oldidx[pos] = i;
        } else remap[i] = -1;
    }
    if (gsum){
        if (t < 512) gsum[t] = 0.f;
        if (t == 0) *done = 0;
        float s = (t < 512) ? w[t] * w[t] : 0.f;
#pragma unroll
        for (int off = 32; off > 0; off >>= 1) s += __shfl_xor(s, off);
        if ((t & 63) == 0) red2[wv] = s;
        __syncthreads();
        if (t == 0){
            float a = 0.f;
            for (int i = 0; i < 16; ++i) a += red2[i];
            *invn = rsqrtf(a);
        }
    }
}

// --------- readout: mean-pool reduce + final 512x10 GEMM (last block) -------
__global__ __launch_bounds__(512) void final_reduce(const float* __restrict__ x,
        const int* __restrict__ oldidx, const float* __restrict__ score, int k,
        float* __restrict__ gsum, int* __restrict__ done,
        const float* __restrict__ Wl, const float* __restrict__ bl,
        float* __restrict__ out)
{
    __shared__ float gsh[512];
    __shared__ int last;
    int t = threadIdx.x; // 512
    float a = 0.f;
    for (int j = blockIdx.x; j < k; j += gridDim.x){
        int o = oldidx[j];
        a += x[(size_t)o * FDIM + t] * score[o];
    }
    atomicAdd(&gsum[t], a);
    __threadfence();
    if (t == 0) last = (atomicAdd(done, 1) == (int)gridDim.x - 1);
    __syncthreads();
    if (!last) return;
    // last block: atomic reads give coherent view of all partial sums
    gsh[t] = atomicAdd(&gsum[t], 0.f);
    __syncthreads();
    int wv = t >> 6, lane = t & 63;
    for (int w = wv; w < 10; w += 8){
        float s = 0.f;
        for (int f = lane; f < FDIM; f += 64) s += gsh[f] * Wl[f * 10 + w];
#pragma unroll
        for (int off = 32; off > 0; off >>= 1) s += __shfl_xor(s, off);
        if (lane == 0) out[w] = s * (1.0f / K2_KEEP) + bl[w];
    }
}

extern "C" void kernel_launch(void* const* d_in, const int* in_sizes, int n_in,
                              void* d_out, int out_size, void* d_ws, size_t ws_size,
                              hipStream_t stream)
{
    (void)in_sizes; (void)n_in; (void)out_size; (void)ws_size;
    const float* x   = (const float*)d_in[0];
    const int*   ei  = (const int*)  d_in[1];
    const float* W1  = (const float*)d_in[3];
    const float* as1 = (const float*)d_in[4];
    const float* ad1 = (const float*)d_in[5];
    const float* b1  = (const float*)d_in[6];
    const float* pw1 = (const float*)d_in[7];
    const float* W2  = (const float*)d_in[8];
    const float* as2 = (const float*)d_in[9];
    const float* ad2 = (const float*)d_in[10];
    const float* b2  = (const float*)d_in[11];
    const float* pw2 = (const float*)d_in[12];
    const float* Wl  = (const float*)d_in[13];
    const float* bl  = (const float*)d_in[14];
    const int* src1 = ei;
    const int* dst1 = ei + E_EDGES;

    char* wsb = (char*)d_ws;
    size_t off = 0;
    auto alloc = [&](size_t bytes) -> char* {
        char* p = wsb + off;
        off += (bytes + 255) & ~(size_t)255;
        return p;
    };
    float* h1   = (float*)alloc((size_t)N_NODES * FDIM * 4);  // reused: h2 + out2
    float* out1 = (float*)alloc((size_t)N_NODES * FDIM * 4);
    float* asrc = (float*)alloc((size_t)N_NODES * NHEAD * 4);
    float* adst = (float*)alloc((size_t)N_NODES * NHEAD * 4);
    float* score= (float*)alloc((size_t)N_NODES * 4);
    float* invn = (float*)alloc(4);
    int* tmp  = (int*)alloc((size_t)N_NODES * 4);
    int* csr  = (int*)alloc((size_t)N_NODES * BSTRIDE * 4);
    int* remap= (int*)alloc((size_t)N_NODES * 4);
    int* oldi = (int*)alloc((size_t)K1_KEEP * 4);
    float* gsum = (float*)alloc(512 * 4);
    int* done = (int*)alloc(4);
    float* h2   = h1;                            // layer-2 aliases into h1 region
    float* out2 = h1 + (size_t)K1_KEEP * FDIM;   // N*F == 2*K1*F, fits exactly

    // ---- layer 1 (GAT on N nodes, E edges + self loops) ----
    int gx1 = (N_NODES + 63) / 64;
    clear_meta<<<(N_NODES + 255) / 256, 256, 0, stream>>>(tmp, N_NODES, pw1, invn);
    gemm_tile<64, 128, true, false><<<gx1 * 4, 256, 0, stream>>>(x, W1, h1,
            nullptr, nullptr, as1, ad1, asrc, adst, N_NODES);
    edge_fill<<<(E_EDGES + 255) / 256, 256, 0, stream>>>(src1, dst1, E_EDGES, tmp, csr);
    gat_fused<false><<<(N_NODES + 3) / 4, 256, 0, stream>>>(h1, asrc, adst, tmp, csr,
            nullptr, nullptr, b1, pw1, invn, out1, score, N_NODES);

    // ---- pool 1; also preps pw2-norm + gsum/done for fused readout ----
    select_compact<<<1, 1024, 0, stream>>>(score, N_NODES, K1_KEEP, remap, oldi,
                                           gsum, done, pw2, invn);

    // ---- layer 2 (GAT on K1 nodes; edges = L1 buckets filtered via remap) ----
    int gx2 = (K1_KEEP + 63) / 64;
    gemm_tile<512, 64, false, true><<<gx2 * 8, 256, 0, stream>>>(out1, W2, h2,
            oldi, score, nullptr, nullptr, nullptr, nullptr, K1_KEEP);
    attn_scores<<<K1_KEEP, 256, 0, stream>>>(h2, as2, ad2, asrc, adst, K1_KEEP);
    gat_fused<true><<<(K1_KEEP + 3) / 4, 256, 0, stream>>>(h2, asrc, adst, tmp, csr,
            oldi, remap, b2, pw2, invn, out2, score, K1_KEEP);

    // ---- pool 2 + fused readout ----
    select_compact<<<1, 1024, 0, stream>>>(score, K1_KEEP, K2_KEEP, remap, oldi,
                                           nullptr, nullptr, nullptr, nullptr);
    final_reduce<<<64, 512, 0, stream>>>(out2, oldi, score, K2_KEEP, gsum, done,
                                         Wl, bl, (float*)d_out);
}

// Round 15
// 467.613 us; speedup vs baseline: 1.0523x; 1.0166x over previous
//
#include <hip/hip_runtime.h>
#include <math.h>

#define N_NODES 20000
#define E_EDGES 200000
#define K1_KEEP 10000
#define K2_KEEP 5000
#define HIDC 128
#define NHEAD 4
#define FDIM 512   // NHEAD*HIDC
#define NEG 0.2f
#define BSTRIDE 64 // bucket CSR stride; P(deg>64)~e^-64 for Binom(200k,1/20k)
#define SELCAP 20  // keys/thread in select (1024*20 >= 20000)

__device__ __forceinline__ float leaky(float x){ return x > 0.f ? x : NEG * x; }
__device__ __forceinline__ float elu(float x){ return x > 0.f ? x : expm1f(x); }
// monotone float->uint key (ascending)
__device__ __forceinline__ unsigned ordkey(float f){
    unsigned u = __float_as_uint(f);
    return (u & 0x80000000u) ? ~u : (u | 0x80000000u);
}

// ---------------- GEMM: out[n x 512] = A[n x K] @ W[K x 512] ----------------
// 64xCOLB tile / 256 threads / KC=32 LDS stage / 4x(COLB/16) per thread.
// r8-r13 lessons: COLB=64 w/ 1256 blocks is the plateau (~105us, VALU 43% =
// DS-issue cap); raising DS:FMA costs waves/CU and nets zero (r9); MR=8
// collapses occupancy (r7); atomic half-dot attention epilogue slows the
// GEMM more than it saves (r13). Column layout {4tc,(+64)} -> 2-way LDS
// aliasing only (free on CDNA4).
// ATTN (COLB=128 only): fused per-row attention dots (col block == one head).
// GATHER: A row r is gidx[r] scaled by gsc[gidx[r]] (TopK pool gather fused).
// CLEAR: trailing blocks (bid>=ngemm) zero ctmp[cn] and compute cinvn=1/||cw||
//   — folds the old clear_meta launch into this one (r15).
template<int K, int COLB, bool ATTN, bool GATHER, bool CLEAR>
__global__ __launch_bounds__(256) void gemm_tile(const float* __restrict__ A,
        const float* __restrict__ W, float* __restrict__ out,
        const int* __restrict__ gidx, const float* __restrict__ gsc,
        const float* __restrict__ avS, const float* __restrict__ avD,
        float* __restrict__ asrc, float* __restrict__ adst, int n,
        int ngemm, int* __restrict__ ctmp, int cn,
        const float* __restrict__ cw, float* __restrict__ cinvn)
{
    int t = threadIdx.x;
    int bid = blockIdx.x;
    if constexpr (CLEAR){
        if (bid >= ngemm){
            __shared__ float redc[4];
            int b2 = bid - ngemm;
            int i = b2 * 256 + t;
            if (i < cn) ctmp[i] = 0;
            if (b2 == 0){
                float s = cw[t] * cw[t] + cw[t + 256] * cw[t + 256];
#pragma unroll
                for (int off = 32; off > 0; off >>= 1) s += __shfl_xor(s, off);
                if ((t & 63) == 0) redc[t >> 6] = s;
                __syncthreads();
                if (t == 0) *cinvn = rsqrtf(redc[0] + redc[1] + redc[2] + redc[3]);
            }
            return;
        }
    }
    constexpr int NR = COLB / 16;        // 8 or 4 cols per thread
    constexpr int WPT = COLB / 32;       // W-stage float4s per thread (4 or 2)
    constexpr int BPR = 512 / COLB;      // col blocks per row stripe
    __shared__ float At[32][68];         // transposed A tile (16B-aligned rows)
    __shared__ float Wt[32][COLB];
    int row0 = (bid / BPR) * 64;
    int col0 = (bid % BPR) * COLB;
    int tr = t >> 4;       // 0..15 -> rows 4*tr..4*tr+3
    int tc = t & 15;       // cols {col0+4tc.. (+64 for NR==8)}
    float acc[4][NR] = {};

    // loop-invariant row indirection for A staging
    int arow[2]; float asc[2];
#pragma unroll
    for (int i = 0; i < 2; ++i){
        int r = (t + i * 256) >> 3;
        int gr = row0 + r;
        arow[i] = -1; asc[i] = 1.f;
        if (gr < n){
            if (GATHER){ arow[i] = gidx[gr]; asc[i] = gsc[arow[i]]; }
            else arow[i] = gr;
        }
    }

    float4 pa[2], pw[WPT];
    // prefetch first tile
#pragma unroll
    for (int i = 0; i < 2; ++i){
        int kq = (t + i * 256) & 7;
        pa[i] = make_float4(0.f, 0.f, 0.f, 0.f);
        if (arow[i] >= 0){
            pa[i] = *reinterpret_cast<const float4*>(&A[(size_t)arow[i] * K + kq * 4]);
            if (GATHER){ pa[i].x *= asc[i]; pa[i].y *= asc[i]; pa[i].z *= asc[i]; pa[i].w *= asc[i]; }
        }
    }
#pragma unroll
    for (int i = 0; i < WPT; ++i){
        int s = t + i * 256; int k = s / (COLB / 4), c4 = s % (COLB / 4);
        pw[i] = *reinterpret_cast<const float4*>(&W[(size_t)k * 512 + col0 + c4 * 4]);
    }

    for (int kc = 0; kc < K; kc += 32){
        // write staged regs to LDS
#pragma unroll
        for (int i = 0; i < 2; ++i){
            int s = t + i * 256; int r = s >> 3, kq = s & 7;
            At[kq * 4 + 0][r] = pa[i].x;
            At[kq * 4 + 1][r] = pa[i].y;
            At[kq * 4 + 2][r] = pa[i].z;
            At[kq * 4 + 3][r] = pa[i].w;
        }
#pragma unroll
        for (int i = 0; i < WPT; ++i){
            int s = t + i * 256; int k = s / (COLB / 4), c4 = s % (COLB / 4);
            *reinterpret_cast<float4*>(&Wt[k][c4 * 4]) = pw[i];
        }
        __syncthreads();
        if (kc + 32 < K){   // prefetch next tile while computing this one
            int kn = kc + 32;
#pragma unroll
            for (int i = 0; i < 2; ++i){
                int kq = (t + i * 256) & 7;
                pa[i] = make_float4(0.f, 0.f, 0.f, 0.f);
                if (arow[i] >= 0){
                    pa[i] = *reinterpret_cast<const float4*>(&A[(size_t)arow[i] * K + kn + kq * 4]);
                    if (GATHER){ pa[i].x *= asc[i]; pa[i].y *= asc[i]; pa[i].z *= asc[i]; pa[i].w *= asc[i]; }
                }
            }
#pragma unroll
            for (int i = 0; i < WPT; ++i){
                int s = t + i * 256; int k = s / (COLB / 4), c4 = s % (COLB / 4);
                pw[i] = *reinterpret_cast<const float4*>(&W[(size_t)(kn + k) * 512 + col0 + c4 * 4]);
            }
        }
#pragma unroll 8
        for (int kk = 0; kk < 32; ++kk){
            float4 a = *reinterpret_cast<const float4*>(&At[kk][tr * 4]);
            float af[4] = {a.x, a.y, a.z, a.w};
            float wf[NR];
            {
                float4 w0 = *reinterpret_cast<const float4*>(&Wt[kk][tc * 4]);
                wf[0] = w0.x; wf[1] = w0.y; wf[2] = w0.z; wf[3] = w0.w;
                if constexpr (NR == 8){
                    float4 w1 = *reinterpret_cast<const float4*>(&Wt[kk][tc * 4 + 64]);
                    wf[4] = w1.x; wf[5] = w1.y; wf[6] = w1.z; wf[7] = w1.w;
                }
            }
#pragma unroll
            for (int r = 0; r < 4; ++r)
#pragma unroll
                for (int c = 0; c < NR; ++c) acc[r][c] += af[r] * wf[c];
        }
        __syncthreads();
    }
#pragma unroll
    for (int r = 0; r < 4; ++r){
        int gr = row0 + 4 * tr + r;
        if (gr < n){
            *reinterpret_cast<float4*>(&out[(size_t)gr * 512 + col0 + tc * 4]) =
                make_float4(acc[r][0], acc[r][1], acc[r][2], acc[r][3]);
            if constexpr (NR == 8)
                *reinterpret_cast<float4*>(&out[(size_t)gr * 512 + col0 + 64 + tc * 4]) =
                    make_float4(acc[r][4], acc[r][5], acc[r][6], acc[r][7]);
        }
    }
    if constexpr (ATTN){
        int head = col0 >> 7;
        const float* as = avS + head * HIDC;
        const float* ad = avD + head * HIDC;
#pragma unroll
        for (int r = 0; r < 4; ++r){
            float s = 0.f, d = 0.f;
#pragma unroll
            for (int c = 0; c < 4; ++c){
                s += acc[r][c] * as[4 * tc + c];
                d += acc[r][c] * ad[4 * tc + c];
                s += acc[r][4 + c] * as[64 + 4 * tc + c];
                d += acc[r][4 + c] * ad[64 + 4 * tc + c];
            }
#pragma unroll
            for (int off = 1; off < 16; off <<= 1){ s += __shfl_xor(s, off); d += __shfl_xor(d, off); }
            int gr = row0 + 4 * tr + r;
            if (tc == 0 && gr < n){ asrc[gr * 4 + head] = s; adst[gr * 4 + head] = d; }
        }
    }
}

// ------------- attention scores: asrc[n][h], adst[n][h] ---------------------
__global__ __launch_bounds__(256) void attn_scores(const float* __restrict__ h,
        const float* __restrict__ a_src, const float* __restrict__ a_dst,
        float* __restrict__ asrc, float* __restrict__ adst, int n)
{
    int g = blockIdx.x * 4 + (threadIdx.x >> 6);
    int lane = threadIdx.x & 63;
    int node = g >> 2, head = g & 3;
    if (node >= n) return;
    const float* hp = h + (size_t)node * FDIM + head * HIDC;
    float v0 = hp[lane], v1 = hp[lane + 64];
    const float* as = a_src + head * HIDC;
    const float* ad = a_dst + head * HIDC;
    float s = v0 * as[lane] + v1 * as[lane + 64];
    float d = v0 * ad[lane] + v1 * ad[lane + 64];
#pragma unroll
    for (int off = 32; off > 0; off >>= 1){ s += __shfl_xor(s, off); d += __shfl_xor(d, off); }
    if (lane == 0){ asrc[node * 4 + head] = s; adst[node * 4 + head] = d; }
}

// bucketed CSR fill: no count/scan passes needed; tmp returns degrees.
__global__ void edge_fill(const int* __restrict__ src, const int* __restrict__ dst, int e,
                          int* __restrict__ tmp, int* __restrict__ csr){
    int i = blockIdx.x * 256 + threadIdx.x;
    if (i >= e) return;
    int d = dst[i];
    int pos = atomicAdd(&tmp[d], 1);
    if (pos < BSTRIDE) csr[d * BSTRIDE + pos] = src[i];
}

// ---- fused softmax-stats + aggregation + pool score, one wave per node -----
// r10 geometry (1 wave/node; r11/r12 geometry changes lost). r15: stats use
// TWO gather passes instead of three — sidx cached in pass 1, unnormalized
// exps cached in registers during the lsum pass (aexp[4]/sreg[4], deg<=64,
// statically indexed). Aggregation broadcasts shfl(aexp)*shfl(inv) — same
// single multiply as before, bitwise-identical results.
// FILTER: walk LAYER-1 bucket row of oldi[node]; keep srcs with remap>=0
// (exact: removed edges contribute exp->0 in the reference).
template<bool FILTER>
__global__ __launch_bounds__(256) void gat_fused(const float* __restrict__ h,
        const float* __restrict__ asrc, const float* __restrict__ adst,
        const int* __restrict__ degs, const int* __restrict__ csr,
        const int* __restrict__ oldi, const int* __restrict__ remap,
        const float* __restrict__ bias, const float* __restrict__ pw,
        const float* __restrict__ invn, float* __restrict__ out,
        float* __restrict__ score, int n)
{
    int node = blockIdx.x * 4 + (threadIdx.x >> 6);
    int lane = threadIdx.x & 63;
    if (node >= n) return;
    int od = FILTER ? oldi[node] : node;
    int deg = degs[od]; if (deg > BSTRIDE) deg = BSTRIDE;
    int e0 = od * BSTRIDE;
    int ph = lane & 3;
    int pe = lane >> 2;
    float adn  = adst[node * 4 + ph];
    float slog = leaky(asrc[node * 4 + ph] + adn);
    // pass 1: max over edges; cache (remapped) src indices
    int sreg[4];
    float mx = slog;
#pragma unroll
    for (int blk = 0; blk < 4; ++blk){
        int j = blk * 16 + pe;
        int s = -1;
        if (j < deg){
            s = csr[e0 + j];
            if (FILTER) s = remap[s];
            if (s >= 0) mx = fmaxf(mx, leaky(asrc[s * 4 + ph] + adn));
        }
        sreg[blk] = s;
    }
#pragma unroll
    for (int off = 4; off < 64; off <<= 1) mx = fmaxf(mx, __shfl_xor(mx, off));
    // pass 2: exp + cache + sum
    float aexp[4];
    float lsum = 0.f;
#pragma unroll
    for (int blk = 0; blk < 4; ++blk){
        float ex = 0.f;
        int s = sreg[blk];
        if (s >= 0) ex = expf(leaky(asrc[s * 4 + ph] + adn) - mx);
        aexp[blk] = ex;
        lsum += ex;
    }
#pragma unroll
    for (int off = 4; off < 64; off <<= 1) lsum += __shfl_xor(lsum, off);
    float es  = expf(slog - mx);
    float inv = 1.f / (lsum + es);

    int f0 = lane * 8;
    int hf = lane >> 4;
    float invh  = __shfl(inv, hf);       // lane hf holds head hf's stats
    float aself = __shfl(es, hf) * invh;
    float4 acc0, acc1;
    {
        const float4* hp = reinterpret_cast<const float4*>(&h[(size_t)node * FDIM + f0]);
        float4 v0 = hp[0], v1 = hp[1];
        acc0 = make_float4(aself * v0.x, aself * v0.y, aself * v0.z, aself * v0.w);
        acc1 = make_float4(aself * v1.x, aself * v1.y, aself * v1.z, aself * v1.w);
    }
#pragma unroll
    for (int blk = 0; blk < 4; ++blk){
        int base = blk * 16;
        if (base >= deg) break;
        int cnt = deg - base; if (cnt > 16) cnt = 16;
        for (int e = 0; e < cnt; ++e){
            int s = __shfl(sreg[blk], e * 4);
            if (FILTER && s < 0) continue;
            float al = __shfl(aexp[blk], e * 4 + hf) * invh;
            const float4* p = reinterpret_cast<const float4*>(&h[(size_t)s * FDIM + f0]);
            float4 u0 = p[0], u1 = p[1];
            acc0.x += al * u0.x; acc0.y += al * u0.y; acc0.z += al * u0.z; acc0.w += al * u0.w;
            acc1.x += al * u1.x; acc1.y += al * u1.y; acc1.z += al * u1.z; acc1.w += al * u1.w;
        }
    }
    const float4* bp = reinterpret_cast<const float4*>(&bias[f0]);
    float4 b0 = bp[0], b1 = bp[1];
    float4 o0 = make_float4(elu(acc0.x + b0.x), elu(acc0.y + b0.y),
                            elu(acc0.z + b0.z), elu(acc0.w + b0.w));
    float4 o1 = make_float4(elu(acc1.x + b1.x), elu(acc1.y + b1.y),
                            elu(acc1.z + b1.z), elu(acc1.w + b1.w));
    float4* op = reinterpret_cast<float4*>(&out[(size_t)node * FDIM + f0]);
    op[0] = o0; op[1] = o1;
    // fused TopK pool score
    const float4* wp = reinterpret_cast<const float4*>(&pw[f0]);
    float4 w0 = wp[0], w1 = wp[1];
    float s = o0.x * w0.x + o0.y * w0.y + o0.z * w0.z + o0.w * w0.w
            + o1.x * w1.x + o1.y * w1.y + o1.z * w1.z + o1.w * w1.w;
#pragma unroll
    for (int off = 32; off > 0; off >>= 1) s += __shfl_xor(s, off);
    if (lane == 0) score[node] = tanhf(s * (*invn));
}

// ---- exact top-k select (4x 8-bit radix) + compact, single block -----------
// r14: keys staged ONCE into registers (SELCAP=20/thread) — 1 global pass
// instead of 5. Per-wave private LDS histograms. When gsum!=null also: zero
// gsum+done and compute invn=1/||w|| for the next layer's pool.
__global__ __launch_bounds__(1024) void select_compact(const float* __restrict__ score,
        int n, int k, int* __restrict__ remap, int* __restrict__ oldidx,
        float* __restrict__ gsum, int* __restrict__ done,
        const float* __restrict__ w, float* __restrict__ invn)
{
    __shared__ unsigned hist[16][256];
    __shared__ unsigned s_prefix, s_rem, l_tie, l_keep;
    __shared__ float red2[16];
    int t = threadIdx.x;
    int wv = t >> 6;
    unsigned keys[SELCAP];
#pragma unroll
    for (int j = 0; j < SELCAP; ++j){
        int i = t + j * 1024;
        keys[j] = (i < n) ? ordkey(score[i]) : 0u;
    }
    if (t == 0){ s_prefix = 0u; s_rem = (unsigned)k; l_tie = 0u; l_keep = 0u; }
    for (int i = t; i < 16 * 256; i += 1024) ((unsigned*)hist)[i] = 0u;
    __syncthreads();
    for (int pass = 3; pass >= 0; --pass){
        unsigned shift = (unsigned)pass * 8u;
        unsigned pmask = (pass == 3) ? 0u : (0xFFFFFFFFu << (shift + 8u));
        unsigned pref = s_prefix;
#pragma unroll
        for (int j = 0; j < SELCAP; ++j){
            int i = t + j * 1024;
            if (i < n && (keys[j] & pmask) == pref)
                atomicAdd(&hist[wv][(keys[j] >> shift) & 255u], 1u);
        }
        __syncthreads();
        if (t < 256){
            unsigned a = 0;
#pragma unroll
            for (int wq = 0; wq < 16; ++wq) a += hist[wq][t];
            hist[0][t] = a;
        }
        __syncthreads();
        if (t == 0){
            unsigned rem = s_rem, acc = 0, d = 255;
            for (;;){
                unsigned c = hist[0][d];
                if (acc + c >= rem) break;
                acc += c;
                if (d == 0) break;
                --d;
            }
            s_prefix = pref | (d << shift);
            s_rem = rem - acc;
        }
        __syncthreads();
        for (int i = t; i < 16 * 256; i += 1024) ((unsigned*)hist)[i] = 0u;
        __syncthreads();
    }
    unsigned T = s_prefix, ties = s_rem;
#pragma unroll
    for (int j = 0; j < SELCAP; ++j){
        int i = t + j * 1024;
        if (i >= n) continue;
        unsigned key = keys[j];
        int keep = 0;
        if (key > T) keep = 1;
        else if (key == T){
            unsigned tk = atomicAdd(&l_tie, 1u);
            if (tk < ties) keep = 1;
        }
        if (keep){
            int pos = (int)atomicAdd(&l_keep, 1u);
            remap[i] = pos;
            oldidx[pos] = i;
        } else remap[i] = -1;
    }
    if (gsum){
        if (t < 512) gsum[t] = 0.f;
        if (t == 0) *done = 0;
        float s = (t < 512) ? w[t] * w[t] : 0.f;
#pragma unroll
        for (int off = 32; off > 0; off >>= 1) s += __shfl_xor(s, off);
        if ((t & 63) == 0) red2[wv] = s;
        __syncthreads();
        if (t == 0){
            float a = 0.f;
            for (int i = 0; i < 16; ++i) a += red2[i];
            *invn = rsqrtf(a);
        }
    }
}

// --------- readout: mean-pool reduce + final 512x10 GEMM (last block) -------
__global__ __launch_bounds__(512) void final_reduce(const float* __restrict__ x,
        const int* __restrict__ oldidx, const float* __restrict__ score, int k,
        float* __restrict__ gsum, int* __restrict__ done,
        const float* __restrict__ Wl, const float* __restrict__ bl,
        float* __restrict__ out)
{
    __shared__ float gsh[512];
    __shared__ int last;
    int t = threadIdx.x; // 512
    float a = 0.f;
    for (int j = blockIdx.x; j < k; j += gridDim.x){
        int o = oldidx[j];
        a += x[(size_t)o * FDIM + t] * score[o];
    }
    atomicAdd(&gsum[t], a);
    __threadfence();
    if (t == 0) last = (atomicAdd(done, 1) == (int)gridDim.x - 1);
    __syncthreads();
    if (!last) return;
    // last block: atomic reads give coherent view of all partial sums
    gsh[t] = atomicAdd(&gsum[t], 0.f);
    __syncthreads();
    int wv = t >> 6, lane = t & 63;
    for (int w = wv; w < 10; w += 8){
        float s = 0.f;
        for (int f = lane; f < FDIM; f += 64) s += gsh[f] * Wl[f * 10 + w];
#pragma unroll
        for (int off = 32; off > 0; off >>= 1) s += __shfl_xor(s, off);
        if (lane == 0) out[w] = s * (1.0f / K2_KEEP) + bl[w];
    }
}

extern "C" void kernel_launch(void* const* d_in, const int* in_sizes, int n_in,
                              void* d_out, int out_size, void* d_ws, size_t ws_size,
                              hipStream_t stream)
{
    (void)in_sizes; (void)n_in; (void)out_size; (void)ws_size;
    const float* x   = (const float*)d_in[0];
    const int*   ei  = (const int*)  d_in[1];
    const float* W1  = (const float*)d_in[3];
    const float* as1 = (const float*)d_in[4];
    const float* ad1 = (const float*)d_in[5];
    const float* b1  = (const float*)d_in[6];
    const float* pw1 = (const float*)d_in[7];
    const float* W2  = (const float*)d_in[8];
    const float* as2 = (const float*)d_in[9];
    const float* ad2 = (const float*)d_in[10];
    const float* b2  = (const float*)d_in[11];
    const float* pw2 = (const float*)d_in[12];
    const float* Wl  = (const float*)d_in[13];
    const float* bl  = (const float*)d_in[14];
    const int* src1 = ei;
    const int* dst1 = ei + E_EDGES;

    char* wsb = (char*)d_ws;
    size_t off = 0;
    auto alloc = [&](size_t bytes) -> char* {
        char* p = wsb + off;
        off += (bytes + 255) & ~(size_t)255;
        return p;
    };
    float* h1   = (float*)alloc((size_t)N_NODES * FDIM * 4);  // reused: h2 + out2
    float* out1 = (float*)alloc((size_t)N_NODES * FDIM * 4);
    float* asrc = (float*)alloc((size_t)N_NODES * NHEAD * 4);
    float* adst = (float*)alloc((size_t)N_NODES * NHEAD * 4);
    float* score= (float*)alloc((size_t)N_NODES * 4);
    float* invn = (float*)alloc(4);
    int* tmp  = (int*)alloc((size_t)N_NODES * 4);
    int* csr  = (int*)alloc((size_t)N_NODES * BSTRIDE * 4);
    int* remap= (int*)alloc((size_t)N_NODES * 4);
    int* oldi = (int*)alloc((size_t)K1_KEEP * 4);
    float* gsum = (float*)alloc(512 * 4);
    int* done = (int*)alloc(4);
    float* h2   = h1;                            // layer-2 aliases into h1 region
    float* out2 = h1 + (size_t)K1_KEEP * FDIM;   // N*F == 2*K1*F, fits exactly

    // ---- layer 1 (GAT on N nodes, E edges + self loops) ----
    int gx1 = (N_NODES + 63) / 64;
    int ngemm1 = gx1 * 4;
    int nclr = (N_NODES + 255) / 256;
    gemm_tile<64, 128, true, false, true><<<ngemm1 + nclr, 256, 0, stream>>>(x, W1, h1,
            nullptr, nullptr, as1, ad1, asrc, adst, N_NODES,
            ngemm1, tmp, N_NODES, pw1, invn);
    edge_fill<<<(E_EDGES + 255) / 256, 256, 0, stream>>>(src1, dst1, E_EDGES, tmp, csr);
    gat_fused<false><<<(N_NODES + 3) / 4, 256, 0, stream>>>(h1, asrc, adst, tmp, csr,
            nullptr, nullptr, b1, pw1, invn, out1, score, N_NODES);

    // ---- pool 1; also preps pw2-norm + gsum/done for fused readout ----
    select_compact<<<1, 1024, 0, stream>>>(score, N_NODES, K1_KEEP, remap, oldi,
                                           gsum, done, pw2, invn);

    // ---- layer 2 (GAT on K1 nodes; edges = L1 buckets filtered via remap) ----
    int gx2 = (K1_KEEP + 63) / 64;
    gemm_tile<512, 64, false, true, false><<<gx2 * 8, 256, 0, stream>>>(out1, W2, h2,
            oldi, score, nullptr, nullptr, nullptr, nullptr, K1_KEEP,
            0, nullptr, 0, nullptr, nullptr);
    attn_scores<<<K1_KEEP, 256, 0, stream>>>(h2, as2, ad2, asrc, adst, K1_KEEP);
    gat_fused<true><<<(K1_KEEP + 3) / 4, 256, 0, stream>>>(h2, asrc, adst, tmp, csr,
            oldi, remap, b2, pw2, invn, out2, score, K1_KEEP);

    // ---- pool 2 + fused readout ----
    select_compact<<<1, 1024, 0, stream>>>(score, K1_KEEP, K2_KEEP, remap, oldi,
                                           nullptr, nullptr, nullptr, nullptr);
    final_reduce<<<64, 512, 0, stream>>>(out2, oldi, score, K2_KEEP, gsum, done,
                                         Wl, bl, (float*)d_out);
}

// Round 16
// 466.818 us; speedup vs baseline: 1.0541x; 1.0017x over previous
//
#include <hip/hip_runtime.h>
#include <math.h>

#define N_NODES 20000
#define E_EDGES 200000
#define K1_KEEP 10000
#define K2_KEEP 5000
#define HIDC 128
#define NHEAD 4
#define FDIM 512   // NHEAD*HIDC
#define NEG 0.2f
#define BSTRIDE 64 // bucket CSR stride; P(deg>64)~e^-64 for Binom(200k,1/20k)
#define SELCAP 20  // keys/thread in select (1024*20 >= 20000)

__device__ __forceinline__ float leaky(float x){ return x > 0.f ? x : NEG * x; }
__device__ __forceinline__ float elu(float x){ return x > 0.f ? x : expm1f(x); }
// monotone float->uint key (ascending)
__device__ __forceinline__ unsigned ordkey(float f){
    unsigned u = __float_as_uint(f);
    return (u & 0x80000000u) ? ~u : (u | 0x80000000u);
}

// ---------------- GEMM: out[n x 512] = A[n x K] @ W[K x 512] ----------------
// 64xCOLB tile / 256 threads / KC=32 LDS stage / 4x(COLB/16) per thread.
// r8-r13: COLB=64 w/ 1256 blocks is the plateau (~105us, VALU 43% = DS-issue
// cap); raising DS:FMA costs waves/CU and nets zero (r9); MR=8 collapses
// occupancy (r7); ATOMIC attention epilogue loses (r13). Column layout
// {4tc,(+64)} -> 2-way LDS aliasing only (free on CDNA4).
// AMODE 1 (COLB=128): full attention dots in epilogue (col block == head).
// AMODE 2 (COLB=64): NON-ATOMIC half-dots -> asrcH[n][4][2]; each slot is
//   written by exactly one block (plain store, deterministic, no pre-zero).
// GATHER: A row r is gidx[r] scaled by gsc[gidx[r]] (TopK pool gather fused).
// CLEAR: trailing blocks zero ctmp[cn] and compute cinvn=1/||cw|| (r15).
template<int K, int COLB, int AMODE, bool GATHER, bool CLEAR>
__global__ __launch_bounds__(256) void gemm_tile(const float* __restrict__ A,
        const float* __restrict__ W, float* __restrict__ out,
        const int* __restrict__ gidx, const float* __restrict__ gsc,
        const float* __restrict__ avS, const float* __restrict__ avD,
        float* __restrict__ asrc, float* __restrict__ adst, int n,
        int ngemm, int* __restrict__ ctmp, int cn,
        const float* __restrict__ cw, float* __restrict__ cinvn)
{
    int t = threadIdx.x;
    int bid = blockIdx.x;
    if constexpr (CLEAR){
        if (bid >= ngemm){
            __shared__ float redc[4];
            int b2 = bid - ngemm;
            int i = b2 * 256 + t;
            if (i < cn) ctmp[i] = 0;
            if (b2 == 0){
                float s = cw[t] * cw[t] + cw[t + 256] * cw[t + 256];
#pragma unroll
                for (int off = 32; off > 0; off >>= 1) s += __shfl_xor(s, off);
                if ((t & 63) == 0) redc[t >> 6] = s;
                __syncthreads();
                if (t == 0) *cinvn = rsqrtf(redc[0] + redc[1] + redc[2] + redc[3]);
            }
            return;
        }
    }
    constexpr int NR = COLB / 16;        // 8 or 4 cols per thread
    constexpr int WPT = COLB / 32;       // W-stage float4s per thread (4 or 2)
    constexpr int BPR = 512 / COLB;      // col blocks per row stripe
    __shared__ float At[32][68];         // transposed A tile (16B-aligned rows)
    __shared__ float Wt[32][COLB];
    int row0 = (bid / BPR) * 64;
    int col0 = (bid % BPR) * COLB;
    int tr = t >> 4;       // 0..15 -> rows 4*tr..4*tr+3
    int tc = t & 15;       // cols {col0+4tc.. (+64 for NR==8)}
    float acc[4][NR] = {};

    // loop-invariant row indirection for A staging
    int arow[2]; float asc[2];
#pragma unroll
    for (int i = 0; i < 2; ++i){
        int r = (t + i * 256) >> 3;
        int gr = row0 + r;
        arow[i] = -1; asc[i] = 1.f;
        if (gr < n){
            if (GATHER){ arow[i] = gidx[gr]; asc[i] = gsc[arow[i]]; }
            else arow[i] = gr;
        }
    }

    float4 pa[2], pw[WPT];
    // prefetch first tile
#pragma unroll
    for (int i = 0; i < 2; ++i){
        int kq = (t + i * 256) & 7;
        pa[i] = make_float4(0.f, 0.f, 0.f, 0.f);
        if (arow[i] >= 0){
            pa[i] = *reinterpret_cast<const float4*>(&A[(size_t)arow[i] * K + kq * 4]);
            if (GATHER){ pa[i].x *= asc[i]; pa[i].y *= asc[i]; pa[i].z *= asc[i]; pa[i].w *= asc[i]; }
        }
    }
#pragma unroll
    for (int i = 0; i < WPT; ++i){
        int s = t + i * 256; int k = s / (COLB / 4), c4 = s % (COLB / 4);
        pw[i] = *reinterpret_cast<const float4*>(&W[(size_t)k * 512 + col0 + c4 * 4]);
    }

    for (int kc = 0; kc < K; kc += 32){
        // write staged regs to LDS
#pragma unroll
        for (int i = 0; i < 2; ++i){
            int s = t + i * 256; int r = s >> 3, kq = s & 7;
            At[kq * 4 + 0][r] = pa[i].x;
            At[kq * 4 + 1][r] = pa[i].y;
            At[kq * 4 + 2][r] = pa[i].z;
            At[kq * 4 + 3][r] = pa[i].w;
        }
#pragma unroll
        for (int i = 0; i < WPT; ++i){
            int s = t + i * 256; int k = s / (COLB / 4), c4 = s % (COLB / 4);
            *reinterpret_cast<float4*>(&Wt[k][c4 * 4]) = pw[i];
        }
        __syncthreads();
        if (kc + 32 < K){   // prefetch next tile while computing this one
            int kn = kc + 32;
#pragma unroll
            for (int i = 0; i < 2; ++i){
                int kq = (t + i * 256) & 7;
                pa[i] = make_float4(0.f, 0.f, 0.f, 0.f);
                if (arow[i] >= 0){
                    pa[i] = *reinterpret_cast<const float4*>(&A[(size_t)arow[i] * K + kn + kq * 4]);
                    if (GATHER){ pa[i].x *= asc[i]; pa[i].y *= asc[i]; pa[i].z *= asc[i]; pa[i].w *= asc[i]; }
                }
            }
#pragma unroll
            for (int i = 0; i < WPT; ++i){
                int s = t + i * 256; int k = s / (COLB / 4), c4 = s % (COLB / 4);
                pw[i] = *reinterpret_cast<const float4*>(&W[(size_t)(kn + k) * 512 + col0 + c4 * 4]);
            }
        }
#pragma unroll 8
        for (int kk = 0; kk < 32; ++kk){
            float4 a = *reinterpret_cast<const float4*>(&At[kk][tr * 4]);
            float af[4] = {a.x, a.y, a.z, a.w};
            float wf[NR];
            {
                float4 w0 = *reinterpret_cast<const float4*>(&Wt[kk][tc * 4]);
                wf[0] = w0.x; wf[1] = w0.y; wf[2] = w0.z; wf[3] = w0.w;
                if constexpr (NR == 8){
                    float4 w1 = *reinterpret_cast<const float4*>(&Wt[kk][tc * 4 + 64]);
                    wf[4] = w1.x; wf[5] = w1.y; wf[6] = w1.z; wf[7] = w1.w;
                }
            }
#pragma unroll
            for (int r = 0; r < 4; ++r)
#pragma unroll
                for (int c = 0; c < NR; ++c) acc[r][c] += af[r] * wf[c];
        }
        __syncthreads();
    }
#pragma unroll
    for (int r = 0; r < 4; ++r){
        int gr = row0 + 4 * tr + r;
        if (gr < n){
            *reinterpret_cast<float4*>(&out[(size_t)gr * 512 + col0 + tc * 4]) =
                make_float4(acc[r][0], acc[r][1], acc[r][2], acc[r][3]);
            if constexpr (NR == 8)
                *reinterpret_cast<float4*>(&out[(size_t)gr * 512 + col0 + 64 + tc * 4]) =
                    make_float4(acc[r][4], acc[r][5], acc[r][6], acc[r][7]);
        }
    }
    if constexpr (AMODE == 1){
        int head = col0 >> 7;
        const float* as = avS + head * HIDC;
        const float* ad = avD + head * HIDC;
#pragma unroll
        for (int r = 0; r < 4; ++r){
            float s = 0.f, d = 0.f;
#pragma unroll
            for (int c = 0; c < 4; ++c){
                s += acc[r][c] * as[4 * tc + c];
                d += acc[r][c] * ad[4 * tc + c];
                s += acc[r][4 + c] * as[64 + 4 * tc + c];
                d += acc[r][4 + c] * ad[64 + 4 * tc + c];
            }
#pragma unroll
            for (int off = 1; off < 16; off <<= 1){ s += __shfl_xor(s, off); d += __shfl_xor(d, off); }
            int gr = row0 + 4 * tr + r;
            if (tc == 0 && gr < n){ asrc[gr * 4 + head] = s; adst[gr * 4 + head] = d; }
        }
    }
    if constexpr (AMODE == 2){
        int head = col0 >> 7;
        int half = (col0 >> 6) & 1;
        const float* as = avS + head * HIDC + half * 64;
        const float* ad = avD + head * HIDC + half * 64;
#pragma unroll
        for (int r = 0; r < 4; ++r){
            float s = 0.f, d = 0.f;
#pragma unroll
            for (int c = 0; c < 4; ++c){
                s += acc[r][c] * as[4 * tc + c];
                d += acc[r][c] * ad[4 * tc + c];
            }
#pragma unroll
            for (int off = 1; off < 16; off <<= 1){ s += __shfl_xor(s, off); d += __shfl_xor(d, off); }
            int gr = row0 + 4 * tr + r;
            if (tc == 0 && gr < n){
                asrc[gr * 8 + head * 2 + half] = s;   // plain store: 1 writer/slot
                adst[gr * 8 + head * 2 + half] = d;
            }
        }
    }
}

// bucketed CSR fill: no count/scan passes needed; tmp returns degrees.
__global__ void edge_fill(const int* __restrict__ src, const int* __restrict__ dst, int e,
                          int* __restrict__ tmp, int* __restrict__ csr){
    int i = blockIdx.x * 256 + threadIdx.x;
    if (i >= e) return;
    int d = dst[i];
    int pos = atomicAdd(&tmp[d], 1);
    if (pos < BSTRIDE) csr[d * BSTRIDE + pos] = src[i];
}

// ---- fused softmax-stats + aggregation + pool score, one wave per node -----
// r10 geometry (1 wave/node; r11/r12 geometry changes lost). r15 stats: TWO
// gather passes — sidx cached in pass 1, unnormalized exps cached in regs
// during the lsum pass. HALF (==FILTER, layer 2): attention values stored as
// half-dot pairs [n][4][2] by GEMM2's epilogue; read as float2 and summed.
// FILTER: walk LAYER-1 bucket row of oldi[node]; keep srcs with remap>=0
// (exact: removed edges contribute exp->0 in the reference).
template<bool FILTER>
__global__ __launch_bounds__(256) void gat_fused(const float* __restrict__ h,
        const float* __restrict__ asrc, const float* __restrict__ adst,
        const int* __restrict__ degs, const int* __restrict__ csr,
        const int* __restrict__ oldi, const int* __restrict__ remap,
        const float* __restrict__ bias, const float* __restrict__ pw,
        const float* __restrict__ invn, float* __restrict__ out,
        float* __restrict__ score, int n)
{
    int node = blockIdx.x * 4 + (threadIdx.x >> 6);
    int lane = threadIdx.x & 63;
    if (node >= n) return;
    int od = FILTER ? oldi[node] : node;
    int deg = degs[od]; if (deg > BSTRIDE) deg = BSTRIDE;
    int e0 = od * BSTRIDE;
    int ph = lane & 3;
    int pe = lane >> 2;
    float adn, sown;
    if (FILTER){
        float2 dv = *reinterpret_cast<const float2*>(&adst[(size_t)node * 8 + ph * 2]);
        float2 sv = *reinterpret_cast<const float2*>(&asrc[(size_t)node * 8 + ph * 2]);
        adn = dv.x + dv.y; sown = sv.x + sv.y;
    } else {
        adn = adst[node * 4 + ph]; sown = asrc[node * 4 + ph];
    }
    float slog = leaky(sown + adn);
    // pass 1: max over edges; cache (remapped) src indices
    int sreg[4];
    float mx = slog;
#pragma unroll
    for (int blk = 0; blk < 4; ++blk){
        int j = blk * 16 + pe;
        int s = -1;
        if (j < deg){
            s = csr[e0 + j];
            if (FILTER) s = remap[s];
            if (s >= 0){
                float av;
                if (FILTER){
                    float2 v = *reinterpret_cast<const float2*>(&asrc[(size_t)s * 8 + ph * 2]);
                    av = v.x + v.y;
                } else av = asrc[s * 4 + ph];
                mx = fmaxf(mx, leaky(av + adn));
            }
        }
        sreg[blk] = s;
    }
#pragma unroll
    for (int off = 4; off < 64; off <<= 1) mx = fmaxf(mx, __shfl_xor(mx, off));
    // pass 2: exp + cache + sum
    float aexp[4];
    float lsum = 0.f;
#pragma unroll
    for (int blk = 0; blk < 4; ++blk){
        float ex = 0.f;
        int s = sreg[blk];
        if (s >= 0){
            float av;
            if (FILTER){
                float2 v = *reinterpret_cast<const float2*>(&asrc[(size_t)s * 8 + ph * 2]);
                av = v.x + v.y;
            } else av = asrc[s * 4 + ph];
            ex = expf(leaky(av + adn) - mx);
        }
        aexp[blk] = ex;
        lsum += ex;
    }
#pragma unroll
    for (int off = 4; off < 64; off <<= 1) lsum += __shfl_xor(lsum, off);
    float es  = expf(slog - mx);
    float inv = 1.f / (lsum + es);

    int f0 = lane * 8;
    int hf = lane >> 4;
    float invh  = __shfl(inv, hf);       // lane hf holds head hf's stats
    float aself = __shfl(es, hf) * invh;
    float4 acc0, acc1;
    {
        const float4* hp = reinterpret_cast<const float4*>(&h[(size_t)node * FDIM + f0]);
        float4 v0 = hp[0], v1 = hp[1];
        acc0 = make_float4(aself * v0.x, aself * v0.y, aself * v0.z, aself * v0.w);
        acc1 = make_float4(aself * v1.x, aself * v1.y, aself * v1.z, aself * v1.w);
    }
#pragma unroll
    for (int blk = 0; blk < 4; ++blk){
        int base = blk * 16;
        if (base >= deg) break;
        int cnt = deg - base; if (cnt > 16) cnt = 16;
        for (int e = 0; e < cnt; ++e){
            int s = __shfl(sreg[blk], e * 4);
            if (FILTER && s < 0) continue;
            float al = __shfl(aexp[blk], e * 4 + hf) * invh;
            const float4* p = reinterpret_cast<const float4*>(&h[(size_t)s * FDIM + f0]);
            float4 u0 = p[0], u1 = p[1];
            acc0.x += al * u0.x; acc0.y += al * u0.y; acc0.z += al * u0.z; acc0.w += al * u0.w;
            acc1.x += al * u1.x; acc1.y += al * u1.y; acc1.z += al * u1.z; acc1.w += al * u1.w;
        }
    }
    const float4* bp = reinterpret_cast<const float4*>(&bias[f0]);
    float4 b0 = bp[0], b1 = bp[1];
    float4 o0 = make_float4(elu(acc0.x + b0.x), elu(acc0.y + b0.y),
                            elu(acc0.z + b0.z), elu(acc0.w + b0.w));
    float4 o1 = make_float4(elu(acc1.x + b1.x), elu(acc1.y + b1.y),
                            elu(acc1.z + b1.z), elu(acc1.w + b1.w));
    float4* op = reinterpret_cast<float4*>(&out[(size_t)node * FDIM + f0]);
    op[0] = o0; op[1] = o1;
    // fused TopK pool score
    const float4* wp = reinterpret_cast<const float4*>(&pw[f0]);
    float4 w0 = wp[0], w1 = wp[1];
    float s = o0.x * w0.x + o0.y * w0.y + o0.z * w0.z + o0.w * w0.w
            + o1.x * w1.x + o1.y * w1.y + o1.z * w1.z + o1.w * w1.w;
#pragma unroll
    for (int off = 32; off > 0; off >>= 1) s += __shfl_xor(s, off);
    if (lane == 0) score[node] = tanhf(s * (*invn));
}

// ---- exact top-k select (4x 8-bit radix) + compact, single block -----------
// r14: keys staged ONCE into registers (SELCAP=20/thread) — 1 global pass
// instead of 5. Per-wave private LDS histograms. When gsum!=null also: zero
// gsum+done and compute invn=1/||w|| for the next layer's pool.
__global__ __launch_bounds__(1024) void select_compact(const float* __restrict__ score,
        int n, int k, int* __restrict__ remap, int* __restrict__ oldidx,
        float* __restrict__ gsum, int* __restrict__ done,
        const float* __restrict__ w, float* __restrict__ invn)
{
    __shared__ unsigned hist[16][256];
    __shared__ unsigned s_prefix, s_rem, l_tie, l_keep;
    __shared__ float red2[16];
    int t = threadIdx.x;
    int wv = t >> 6;
    unsigned keys[SELCAP];
#pragma unroll
    for (int j = 0; j < SELCAP; ++j){
        int i = t + j * 1024;
        keys[j] = (i < n) ? ordkey(score[i]) : 0u;
    }
    if (t == 0){ s_prefix = 0u; s_rem = (unsigned)k; l_tie = 0u; l_keep = 0u; }
    for (int i = t; i < 16 * 256; i += 1024) ((unsigned*)hist)[i] = 0u;
    __syncthreads();
    for (int pass = 3; pass >= 0; --pass){
        unsigned shift = (unsigned)pass * 8u;
        unsigned pmask = (pass == 3) ? 0u : (0xFFFFFFFFu << (shift + 8u));
        unsigned pref = s_prefix;
#pragma unroll
        for (int j = 0; j < SELCAP; ++j){
            int i = t + j * 1024;
            if (i < n && (keys[j] & pmask) == pref)
                atomicAdd(&hist[wv][(keys[j] >> shift) & 255u], 1u);
        }
        __syncthreads();
        if (t < 256){
            unsigned a = 0;
#pragma unroll
            for (int wq = 0; wq < 16; ++wq) a += hist[wq][t];
            hist[0][t] = a;
        }
        __syncthreads();
        if (t == 0){
            unsigned rem = s_rem, acc = 0, d = 255;
            for (;;){
                unsigned c = hist[0][d];
                if (acc + c >= rem) break;
                acc += c;
                if (d == 0) break;
                --d;
            }
            s_prefix = pref | (d << shift);
            s_rem = rem - acc;
        }
        __syncthreads();
        for (int i = t; i < 16 * 256; i += 1024) ((unsigned*)hist)[i] = 0u;
        __syncthreads();
    }
    unsigned T = s_prefix, ties = s_rem;
#pragma unroll
    for (int j = 0; j < SELCAP; ++j){
        int i = t + j * 1024;
        if (i >= n) continue;
        unsigned key = keys[j];
        int keep = 0;
        if (key > T) keep = 1;
        else if (key == T){
            unsigned tk = atomicAdd(&l_tie, 1u);
            if (tk < ties) keep = 1;
        }
        if (keep){
            int pos = (int)atomicAdd(&l_keep, 1u);
            remap[i] = pos;
            oldidx[pos] = i;
        } else remap[i] = -1;
    }
    if (gsum){
        if (t < 512) gsum[t] = 0.f;
        if (t == 0) *done = 0;
        float s = (t < 512) ? w[t] * w[t] : 0.f;
#pragma unroll
        for (int off = 32; off > 0; off >>= 1) s += __shfl_xor(s, off);
        if ((t & 63) == 0) red2[wv] = s;
        __syncthreads();
        if (t == 0){
            float a = 0.f;
            for (int i = 0; i < 16; ++i) a += red2[i];
            *invn = rsqrtf(a);
        }
    }
}

// --------- readout: mean-pool reduce + final 512x10 GEMM (last block) -------
__global__ __launch_bounds__(512) void final_reduce(const float* __restrict__ x,
        const int* __restrict__ oldidx, const float* __restrict__ score, int k,
        float* __restrict__ gsum, int* __restrict__ done,
        const float* __restrict__ Wl, const float* __restrict__ bl,
        float* __restrict__ out)
{
    __shared__ float gsh[512];
    __shared__ int last;
    int t = threadIdx.x; // 512
    float a = 0.f;
    for (int j = blockIdx.x; j < k; j += gridDim.x){
        int o = oldidx[j];
        a += x[(size_t)o * FDIM + t] * score[o];
    }
    atomicAdd(&gsum[t], a);
    __threadfence();
    if (t == 0) last = (atomicAdd(done, 1) == (int)gridDim.x - 1);
    __syncthreads();
    if (!last) return;
    // last block: atomic reads give coherent view of all partial sums
    gsh[t] = atomicAdd(&gsum[t], 0.f);
    __syncthreads();
    int wv = t >> 6, lane = t & 63;
    for (int w = wv; w < 10; w += 8){
        float s = 0.f;
        for (int f = lane; f < FDIM; f += 64) s += gsh[f] * Wl[f * 10 + w];
#pragma unroll
        for (int off = 32; off > 0; off >>= 1) s += __shfl_xor(s, off);
        if (lane == 0) out[w] = s * (1.0f / K2_KEEP) + bl[w];
    }
}

extern "C" void kernel_launch(void* const* d_in, const int* in_sizes, int n_in,
                              void* d_out, int out_size, void* d_ws, size_t ws_size,
                              hipStream_t stream)
{
    (void)in_sizes; (void)n_in; (void)out_size; (void)ws_size;
    const float* x   = (const float*)d_in[0];
    const int*   ei  = (const int*)  d_in[1];
    const float* W1  = (const float*)d_in[3];
    const float* as1 = (const float*)d_in[4];
    const float* ad1 = (const float*)d_in[5];
    const float* b1  = (const float*)d_in[6];
    const float* pw1 = (const float*)d_in[7];
    const float* W2  = (const float*)d_in[8];
    const float* as2 = (const float*)d_in[9];
    const float* ad2 = (const float*)d_in[10];
    const float* b2  = (const float*)d_in[11];
    const float* pw2 = (const float*)d_in[12];
    const float* Wl  = (const float*)d_in[13];
    const float* bl  = (const float*)d_in[14];
    const int* src1 = ei;
    const int* dst1 = ei + E_EDGES;

    char* wsb = (char*)d_ws;
    size_t off = 0;
    auto alloc = [&](size_t bytes) -> char* {
        char* p = wsb + off;
        off += (bytes + 255) & ~(size_t)255;
        return p;
    };
    float* h1   = (float*)alloc((size_t)N_NODES * FDIM * 4);  // reused: h2 + out2
    float* out1 = (float*)alloc((size_t)N_NODES * FDIM * 4);
    float* asrc = (float*)alloc((size_t)N_NODES * NHEAD * 4); // L2: asrcH[K1][4][2]
    float* adst = (float*)alloc((size_t)N_NODES * NHEAD * 4); // L2: adstH[K1][4][2]
    float* score= (float*)alloc((size_t)N_NODES * 4);
    float* invn = (float*)alloc(4);
    int* tmp  = (int*)alloc((size_t)N_NODES * 4);
    int* csr  = (int*)alloc((size_t)N_NODES * BSTRIDE * 4);
    int* remap= (int*)alloc((size_t)N_NODES * 4);
    int* oldi = (int*)alloc((size_t)K1_KEEP * 4);
    float* gsum = (float*)alloc(512 * 4);
    int* done = (int*)alloc(4);
    float* h2   = h1;                            // layer-2 aliases into h1 region
    float* out2 = h1 + (size_t)K1_KEEP * FDIM;   // N*F == 2*K1*F, fits exactly

    // ---- layer 1 (GAT on N nodes, E edges + self loops) ----
    int gx1 = (N_NODES + 63) / 64;
    int ngemm1 = gx1 * 4;
    int nclr = (N_NODES + 255) / 256;
    gemm_tile<64, 128, 1, false, true><<<ngemm1 + nclr, 256, 0, stream>>>(x, W1, h1,
            nullptr, nullptr, as1, ad1, asrc, adst, N_NODES,
            ngemm1, tmp, N_NODES, pw1, invn);
    edge_fill<<<(E_EDGES + 255) / 256, 256, 0, stream>>>(src1, dst1, E_EDGES, tmp, csr);
    gat_fused<false><<<(N_NODES + 3) / 4, 256, 0, stream>>>(h1, asrc, adst, tmp, csr,
            nullptr, nullptr, b1, pw1, invn, out1, score, N_NODES);

    // ---- pool 1; also preps pw2-norm + gsum/done for fused readout ----
    select_compact<<<1, 1024, 0, stream>>>(score, N_NODES, K1_KEEP, remap, oldi,
                                           gsum, done, pw2, invn);

    // ---- layer 2 (GAT on K1 nodes; edges = L1 buckets filtered via remap) ----
    // attention dots fused into GEMM2 epilogue as non-atomic half-dot stores
    int gx2 = (K1_KEEP + 63) / 64;
    gemm_tile<512, 64, 2, true, false><<<gx2 * 8, 256, 0, stream>>>(out1, W2, h2,
            oldi, score, as2, ad2, asrc, adst, K1_KEEP,
            0, nullptr, 0, nullptr, nullptr);
    gat_fused<true><<<(K1_KEEP + 3) / 4, 256, 0, stream>>>(h2, asrc, adst, tmp, csr,
            oldi, remap, b2, pw2, invn, out2, score, K1_KEEP);

    // ---- pool 2 + fused readout ----
    select_compact<<<1, 1024, 0, stream>>>(score, K1_KEEP, K2_KEEP, remap, oldi,
                                           nullptr, nullptr, nullptr, nullptr);
    final_reduce<<<64, 512, 0, stream>>>(out2, oldi, score, K2_KEEP, gsum, done,
                                         Wl, bl, (float*)d_out);
}